// Round 17
// baseline (231.116 us; speedup 1.0000x reference)
//
#include <hip/hip_runtime.h>
#include <hip/hip_bf16.h>

typedef __attribute__((ext_vector_type(4))) float f32x4;
typedef __attribute__((ext_vector_type(16))) float f32x16;
typedef __attribute__((ext_vector_type(8))) short s16x8;
typedef __attribute__((ext_vector_type(4))) short s16x4;
typedef __attribute__((ext_vector_type(2))) unsigned int u32x2;

__device__ __forceinline__ float fexp2(float x) {   // 2^x
    float y; asm("v_exp_f32 %0, %1" : "=v"(y) : "v"(x)); return y;
}

// ---------------- RoPE tables + mask bias (merged prep) ----------------
__global__ void tables_prep(float* __restrict__ cosT, float* __restrict__ sinT,
                            const int* __restrict__ mask, float* __restrict__ mb) {
    const int bid = blockIdx.x;
    if (bid < 2048) {
        const int s = bid, j = threadIdx.x;             // j in [0,64)
        const float inv = exp2f(-(float)j * (13.287712379549449f / 64.f)); // 10000^(-j/64)
        const float f = (float)s * inv;
        cosT[s * 64 + j] = cosf(f);
        sinT[s * 64 + j] = sinf(f);
    } else {
        const int base = (bid - 2048) * 64 + threadIdx.x;   // 16 blocks x 64 thr
#pragma unroll
        for (int k = 0; k < 4; ++k)
            mb[base + k * 1024] = (mask[base + k * 1024] == 0) ? -1e30f : 0.f;
    }
}

// ---------------- cast fp32 -> bf16 (vectorized) ----------------
__global__ __launch_bounds__(256)
void cast_f32_bf16(const float* __restrict__ src, __hip_bfloat16* __restrict__ dst, int n4) {
    const int i = blockIdx.x * 256 + threadIdx.x;
    if (i < n4) {
        f32x4 v = *reinterpret_cast<const f32x4*>(src + (size_t)i * 4);
        union { s16x4 v4; __hip_bfloat16 h[4]; } u;
#pragma unroll
        for (int j = 0; j < 4; ++j) u.h[j] = __float2bfloat16(v[j]);
        *reinterpret_cast<s16x4*>(dst + (size_t)i * 4) = u.v4;
    }
}

// ---------------- fused weight transposes: Wq|Wk|Wv -> wqkv_t, Wo -> wo_t ----------------
__global__ __launch_bounds__(256)
void transpose_cast_all(const float* __restrict__ Wq, const float* __restrict__ Wk,
                        const float* __restrict__ Wv, const float* __restrict__ Wo,
                        __hip_bfloat16* __restrict__ wqkv_t, __hip_bfloat16* __restrict__ wo_t) {
    __shared__ __align__(16) float t[32][33];
    const int tx = threadIdx.x, ty = threadIdx.y;       // (32, 8)
    const int xseg = blockIdx.x;                        // 0..159
    const int r0 = blockIdx.y * 32;                     // source row base, R = 2048 always
    const float* src; __hip_bfloat16* dst; int C, c0;
    if (xseg < 64)      { src = Wq; dst = wqkv_t;                  C = 2048; c0 = xseg * 32; }
    else if (xseg < 80) { src = Wk; dst = wqkv_t + 2048ULL * 2048; C = 512;  c0 = (xseg - 64) * 32; }
    else if (xseg < 96) { src = Wv; dst = wqkv_t + 2560ULL * 2048; C = 512;  c0 = (xseg - 80) * 32; }
    else                { src = Wo; dst = wo_t;                    C = 2048; c0 = (xseg - 96) * 32; }
#pragma unroll
    for (int i = 0; i < 32; i += 8)
        t[ty + i][tx] = src[(size_t)(r0 + ty + i) * C + c0 + tx];
    __syncthreads();
#pragma unroll
    for (int i = 0; i < 32; i += 8)
        dst[(size_t)(c0 + ty + i) * 2048 + r0 + tx] = __float2bfloat16(t[tx][ty + i]);
}

// ---------------- V slice of bf16 qkv -> Vt[b][hh][d][s] (bit-copy transpose) ----------------
__global__ __launch_bounds__(256)
void vt_transpose(const __hip_bfloat16* __restrict__ qkv, __hip_bfloat16* __restrict__ Vt) {
    __shared__ unsigned short t[32][33];
    const int tx = threadIdx.x, ty = threadIdx.y;       // (32, 8)
    const int s0 = blockIdx.x * 32, d0 = blockIdx.y * 32;
    const int bh = blockIdx.z, b = bh >> 2, hh = bh & 3;
    const unsigned short* q = (const unsigned short*)qkv;
#pragma unroll
    for (int i = 0; i < 32; i += 8)
        t[ty + i][tx] = q[(size_t)(b * 2048 + s0 + ty + i) * 3072 + 2560 + hh * 128 + d0 + tx];
    __syncthreads();
#pragma unroll
    for (int i = 0; i < 32; i += 8)
        ((unsigned short*)Vt)[((size_t)(bh * 128) + d0 + ty + i) * 2048 + s0 + tx] = t[tx][ty + i];
}

// ---------------- 256-row-tile GEMM, counted-vmcnt 4-slot pipeline (T4) ----------
// NI = per-wave N fragments: 4 -> BN=256, 3 -> BN=192, 2 -> BN=128.
template<int NI, bool BF16OUT>
__global__ __launch_bounds__(512, 1)
void gemm256_bt(const __hip_bfloat16* __restrict__ A,
                const __hip_bfloat16* __restrict__ Bt,
                void* __restrict__ Cv, int M, int N, int K, int NX) {
    __shared__ __align__(16) __hip_bfloat16 sm[4][2][8192];
    const int tid = threadIdx.x;
    const int l = tid & 63, w = tid >> 6;               // 8 waves
    const int lo = l & 15, hi = l >> 4;
    const int wm = w >> 2, wn = w & 3;
    const int id = blockIdx.x, slot = id >> 3;
    const int by = (id & 7) * 2 + slot / NX;
    const int bx = slot % NX;
    const int row0 = by * 256;
    const int col0 = bx * (NI * 64);
    const int nk = K >> 5;

    f32x4 acc[8][NI];
#pragma unroll
    for (int mi = 0; mi < 8; ++mi)
#pragma unroll
        for (int ni = 0; ni < NI; ++ni) acc[mi][ni] = f32x4{0.f, 0.f, 0.f, 0.f};

    auto ldlds = [&](const __hip_bfloat16* gsrc, __hip_bfloat16* ldst) {
        __builtin_amdgcn_global_load_lds(
            (const __attribute__((address_space(1))) void*)gsrc,
            (__attribute__((address_space(3))) void*)ldst, 16, 0, 0);
    };
    auto stage = [&](int kt) {
        const int s = kt & 3, k0 = kt << 5;
#pragma unroll
        for (int i = 0; i < 2; ++i) {                   // A: 256 rows x 4 chunks
            const int c = i * 512 + tid;
            const int r = c >> 2, sw = ((c & 3) ^ ((r >> 1) & 3)) * 8;
            ldlds(A + (size_t)(row0 + r) * K + k0 + sw, &sm[s][0][c * 8]);
        }
        {                                               // B chunk set 0: 0..511
            const int c = tid;
            const int r = c >> 2, sw = ((c & 3) ^ ((r >> 1) & 3)) * 8;
            ldlds(Bt + (size_t)(col0 + r) * K + k0 + sw, &sm[s][1][c * 8]);
        }
        if constexpr (NI == 4) {                        // B chunks 512..1023
            const int c = 512 + tid;
            const int r = c >> 2, sw = ((c & 3) ^ ((r >> 1) & 3)) * 8;
            ldlds(Bt + (size_t)(col0 + r) * K + k0 + sw, &sm[s][1][c * 8]);
        } else if constexpr (NI == 3) {                 // B chunks 512..767 (waves 0-3)
            if (tid < 256) {
                const int c = 512 + tid;
                const int r = c >> 2, sw = ((c & 3) ^ ((r >> 1) & 3)) * 8;
                ldlds(Bt + (size_t)(col0 + r) * K + k0 + sw, &sm[s][1][c * 8]);
            }
        }
    };

    stage(0); stage(1); stage(2);                       // 3 tiles ahead
    for (int kt = 0; kt < nk; ++kt) {
        const int s = kt & 3;
        if (kt < nk - 2) {
            if constexpr (NI == 4)      asm volatile("s_waitcnt vmcnt(8)" ::: "memory");
            else if constexpr (NI == 2) asm volatile("s_waitcnt vmcnt(6)" ::: "memory");
            else { if (tid < 256) asm volatile("s_waitcnt vmcnt(8)" ::: "memory");
                   else           asm volatile("s_waitcnt vmcnt(6)" ::: "memory"); }
        } else if (kt == nk - 2) {
            if constexpr (NI == 4)      asm volatile("s_waitcnt vmcnt(4)" ::: "memory");
            else if constexpr (NI == 2) asm volatile("s_waitcnt vmcnt(3)" ::: "memory");
            else { if (tid < 256) asm volatile("s_waitcnt vmcnt(4)" ::: "memory");
                   else           asm volatile("s_waitcnt vmcnt(3)" ::: "memory"); }
        } else {
            asm volatile("s_waitcnt vmcnt(0)" ::: "memory");
        }
        asm volatile("s_waitcnt lgkmcnt(0)" ::: "memory");  // slot reads of kt-1 done
        asm volatile("s_barrier" ::: "memory");             // no compiler drain added
        if (kt + 3 < nk) stage(kt + 3);                     // into slot (kt-1)&3: safe

        s16x8 af[8], bf[NI];
        const int rsw = ((lo >> 1) & 3);                // f(row), row base %16 == 0
#pragma unroll
        for (int mi = 0; mi < 8; ++mi)
            af[mi] = *reinterpret_cast<const s16x8*>(
                &sm[s][0][(wm * 128 + mi * 16 + lo) * 32 + ((hi ^ rsw) * 8)]);
#pragma unroll
        for (int ni = 0; ni < NI; ++ni)
            bf[ni] = *reinterpret_cast<const s16x8*>(
                &sm[s][1][(wn * NI * 16 + ni * 16 + lo) * 32 + ((hi ^ rsw) * 8)]);
        __builtin_amdgcn_s_setprio(1);
#pragma unroll
        for (int mi = 0; mi < 8; ++mi)
#pragma unroll
            for (int ni = 0; ni < NI; ++ni)
                acc[mi][ni] = __builtin_amdgcn_mfma_f32_16x16x32_bf16(af[mi], bf[ni], acc[mi][ni], 0, 0, 0);
        __builtin_amdgcn_s_setprio(0);
    }
    const int rbase = row0 + wm * 128 + hi * 4;
    const int cbase = col0 + wn * NI * 16 + lo;
    if constexpr (BF16OUT) {
        __hip_bfloat16* C = (__hip_bfloat16*)Cv;
#pragma unroll
        for (int mi = 0; mi < 8; ++mi)
#pragma unroll
            for (int ni = 0; ni < NI; ++ni)
#pragma unroll
                for (int r = 0; r < 4; ++r)
                    C[(size_t)(rbase + mi * 16 + r) * N + cbase + ni * 16] =
                        __float2bfloat16(acc[mi][ni][r]);
    } else {
        float* C = (float*)Cv;
#pragma unroll
        for (int mi = 0; mi < 8; ++mi)
#pragma unroll
            for (int ni = 0; ni < NI; ++ni)
#pragma unroll
                for (int r = 0; r < 4; ++r)
                    C[(size_t)(rbase + mi * 16 + r) * N + cbase + ni * 16] = acc[mi][ni][r];
    }
}

// ---------------- 128x256-tile GEMM (Wo): compute-fed ratio, 1 block/CU ----------
// BN=128 (NI=2) was LDS-port-bound: 16 MFMA : 10 reads = 3277 FLOP/LDS-cyc < 3380
// MFMA rate. 128x256 gives 16 MFMA : 8 reads = 4096 FLOP/cyc (compute-fed) AND
// grid (8,32) = 256 blocks = 1/CU. LDS 96KB: A[128][32] + B[256][32] x 4 slots.
__global__ __launch_bounds__(512, 1)
void gemm128x256_bt(const __hip_bfloat16* __restrict__ A,
                    const __hip_bfloat16* __restrict__ Bt,
                    float* __restrict__ C, int M, int N, int K) {
    __shared__ __align__(16) __hip_bfloat16 smA[4][4096];
    __shared__ __align__(16) __hip_bfloat16 smB[4][8192];
    const int tid = threadIdx.x;
    const int l = tid & 63, w = tid >> 6;               // 8 waves: 2M x 4N
    const int lo = l & 15, hi = l >> 4;
    const int wm = w >> 2, wn = w & 3;
    // XCD-chunked: NY=32 rows, each XCD owns 4 consecutive rows; NX=8
    const int id = blockIdx.x, slot = id >> 3;
    const int by = (id & 7) * 4 + slot / 8;
    const int bx = slot % 8;
    const int row0 = by * 128;
    const int col0 = bx * 256;
    const int nk = K >> 5;                              // 64

    f32x4 acc[4][4];
#pragma unroll
    for (int mi = 0; mi < 4; ++mi)
#pragma unroll
        for (int ni = 0; ni < 4; ++ni) acc[mi][ni] = f32x4{0.f, 0.f, 0.f, 0.f};

    auto ldlds = [&](const __hip_bfloat16* gsrc, __hip_bfloat16* ldst) {
        __builtin_amdgcn_global_load_lds(
            (const __attribute__((address_space(1))) void*)gsrc,
            (__attribute__((address_space(3))) void*)ldst, 16, 0, 0);
    };
    auto stage = [&](int kt) {
        const int s = kt & 3, k0 = kt << 5;
        {                                               // A: 128 rows x 4 chunks = 512
            const int c = tid;
            const int r = c >> 2, sw = ((c & 3) ^ ((r >> 1) & 3)) * 8;
            ldlds(A + (size_t)(row0 + r) * K + k0 + sw, &smA[s][c * 8]);
        }
#pragma unroll
        for (int i = 0; i < 2; ++i) {                   // B: 256 rows x 4 chunks = 1024
            const int c = i * 512 + tid;
            const int r = c >> 2, sw = ((c & 3) ^ ((r >> 1) & 3)) * 8;
            ldlds(Bt + (size_t)(col0 + r) * K + k0 + sw, &smB[s][c * 8]);
        }
    };

    stage(0); stage(1); stage(2);                       // 9 loads in flight
    for (int kt = 0; kt < nk; ++kt) {
        const int s = kt & 3;
        if (kt < nk - 2)       asm volatile("s_waitcnt vmcnt(6)" ::: "memory");
        else if (kt == nk - 2) asm volatile("s_waitcnt vmcnt(3)" ::: "memory");
        else                   asm volatile("s_waitcnt vmcnt(0)" ::: "memory");
        asm volatile("s_waitcnt lgkmcnt(0)" ::: "memory");
        asm volatile("s_barrier" ::: "memory");
        if (kt + 3 < nk) stage(kt + 3);

        s16x8 af[4], bf[4];
        const int rsw = ((lo >> 1) & 3);                // row bases % 16 == 0
#pragma unroll
        for (int mi = 0; mi < 4; ++mi)
            af[mi] = *reinterpret_cast<const s16x8*>(
                &smA[s][(wm * 64 + mi * 16 + lo) * 32 + ((hi ^ rsw) * 8)]);
#pragma unroll
        for (int ni = 0; ni < 4; ++ni)
            bf[ni] = *reinterpret_cast<const s16x8*>(
                &smB[s][(wn * 64 + ni * 16 + lo) * 32 + ((hi ^ rsw) * 8)]);
        __builtin_amdgcn_s_setprio(1);
#pragma unroll
        for (int mi = 0; mi < 4; ++mi)
#pragma unroll
            for (int ni = 0; ni < 4; ++ni)
                acc[mi][ni] = __builtin_amdgcn_mfma_f32_16x16x32_bf16(af[mi], bf[ni], acc[mi][ni], 0, 0, 0);
        __builtin_amdgcn_s_setprio(0);
    }
    const int rbase = row0 + wm * 64 + hi * 4;
    const int cbase = col0 + wn * 64 + lo;
#pragma unroll
    for (int mi = 0; mi < 4; ++mi)
#pragma unroll
        for (int ni = 0; ni < 4; ++ni)
#pragma unroll
            for (int r = 0; r < 4; ++r)
                C[(size_t)(rbase + mi * 16 + r) * N + cbase + ni * 16] = acc[mi][ni][r];
}

// ---------------- RoPE + scatter (Q/K only, bf16 in/out, vectorized) ----------------
__global__ __launch_bounds__(256)
void rope_scatter(const __hip_bfloat16* __restrict__ qkv,
                  const float* __restrict__ cosT, const float* __restrict__ sinT,
                  __hip_bfloat16* __restrict__ Qr, __hip_bfloat16* __restrict__ Kr) {
    const int m = blockIdx.y;                           // token row, 0..4095
    const int col4 = blockIdx.x * 256 + threadIdx.x;    // 0..639
    if (col4 >= 640) return;
    const int col = col4 * 4;
    const int b = m >> 11, s = m & 2047;
    const int d = col & 127;                            // 4-aligned
    const int j = d & 63;
    union { s16x4 v4; __hip_bfloat16 h[4]; } vv, pp, u;
    vv.v4 = *reinterpret_cast<const s16x4*>(qkv + (size_t)m * 3072 + col);
    pp.v4 = *reinterpret_cast<const s16x4*>(qkv + (size_t)m * 3072 + (col ^ 64));
    const f32x4 c4 = *reinterpret_cast<const f32x4*>(cosT + s * 64 + j);
    const f32x4 s4 = *reinterpret_cast<const f32x4*>(sinT + s * 64 + j);
    const float sgn = (d < 64) ? -1.f : 1.f;
#pragma unroll
    for (int i = 0; i < 4; ++i)
        u.h[i] = __float2bfloat16(__bfloat162float(vv.h[i]) * c4[i] +
                                  sgn * __bfloat162float(pp.h[i]) * s4[i]);
    if (col < 2048) {
        const int hh = col >> 7;
        *reinterpret_cast<s16x4*>(&Qr[((size_t)(b * 16 + hh) * 2048 + s) * 128 + d]) = u.v4;
    } else {
        const int hh = (col - 2048) >> 7;
        *reinterpret_cast<s16x4*>(&Kr[((size_t)(b * 4 + hh) * 2048 + s) * 128 + d]) = u.v4;
    }
}

// ---------------- flash attention: 4 waves x 32 q-rows, 32x32 MFMA, LDS-free P ----------------
// r14-exact (proven 87.7 us): 2 blocks/CU, 8 waves/CU is the measured optimum of
// the {LDS-port-traffic x latency-hiding} trade. XCD-chunked KV slices L2-resident.
__global__ __launch_bounds__(256, 2)
void attn_kernel(const __hip_bfloat16* __restrict__ Qr,
                 const __hip_bfloat16* __restrict__ Kr,
                 const __hip_bfloat16* __restrict__ Vt,
                 const float* __restrict__ maskb,
                 __hip_bfloat16* __restrict__ Oo) {
    const int S = 2048;
    const int id = blockIdx.x;                          // 0..511
    const int v = (id & 7) * 64 + (id >> 3);            // XCD-chunked, bijective
    const int qt = v & 15;                              // 0..15 (128 q-rows/block)
    const int bh = v >> 4;                              // 0..31
    const int b = bh >> 4, h = bh & 15, kvh = h >> 2;
    const int tid = threadIdx.x;
    const int l = tid & 63, wv_ = tid >> 6;             // 4 waves
    const int lq = l & 31, hi2 = l >> 5;
    __shared__ __align__(16) __hip_bfloat16 Ks[2][64 * 128];   // [kv][d], chunk-swizzled
    __shared__ __align__(16) __hip_bfloat16 Vs[2][128 * 64];   // [d][kv], chunk-swizzled

    const __hip_bfloat16* Qb = Qr + (size_t)(b * 16 + h) * S * 128;
    const __hip_bfloat16* Kb = Kr + (size_t)(b * 4 + kvh) * S * 128;
    const __hip_bfloat16* Vb = Vt + (size_t)(b * 4 + kvh) * 128 * S;
    const float* mrow = maskb + b * S;

    // Q fragments (B-operand): col q = lq, k = d = ks*16 + hi2*8 + j
    const int qrow = qt * 128 + wv_ * 32 + lq;
    s16x8 qf[8];
#pragma unroll
    for (int ks = 0; ks < 8; ++ks)
        qf[ks] = *reinterpret_cast<const s16x8*>(Qb + (size_t)qrow * 128 + ks * 16 + hi2 * 8);

    float m_run = 0.f, l_run = 0.f;                     // exp2-domain; row q = lq lane-local
    f32x16 o[4];                                        // O^T[dv = dt*32+...][q = lq]
#pragma unroll
    for (int dt = 0; dt < 4; ++dt)
#pragma unroll
        for (int r = 0; r < 16; ++r) o[dt][r] = 0.f;
    const float scale2 = 0.12751682f;                   // 1/sqrt(128) * log2(e)

    // staging: 256 threads; K 64x16 chunks, V 128x8 chunks, 4 each
    const int krow = tid >> 4, kc8 = tid & 15;          // rows i*16+krow
    const int koff = (kc8 ^ (krow & 7)) * 8;
    const int vrow = tid >> 3, vc8 = tid & 7;           // rows i*32+vrow
    const int voff = (vc8 ^ (vrow & 7)) * 8;

    s16x8 kreg[4], vreg[4];
    auto load_tile = [&](int kv0) {
#pragma unroll
        for (int i = 0; i < 4; ++i)
            kreg[i] = *reinterpret_cast<const s16x8*>(
                Kb + (size_t)(kv0 + i * 16 + krow) * 128 + kc8 * 8);
#pragma unroll
        for (int i = 0; i < 4; ++i)
            vreg[i] = *reinterpret_cast<const s16x8*>(
                Vb + (size_t)(i * 32 + vrow) * S + kv0 + vc8 * 8);
    };

    auto body = [&](int kt, __hip_bfloat16* Kc, __hip_bfloat16* Vc) {
        const int kv0 = kt * 64;
        // mask bias: kv = kv0 + 32*sub + 8*r4 + 4*hi2 + j
        f32x4 bi[2][4];
#pragma unroll
        for (int sub = 0; sub < 2; ++sub)
#pragma unroll
            for (int r4 = 0; r4 < 4; ++r4)
                bi[sub][r4] = *reinterpret_cast<const f32x4*>(
                    mrow + kv0 + sub * 32 + r4 * 8 + hi2 * 4);
#pragma unroll
        for (int i = 0; i < 4; ++i)
            *reinterpret_cast<s16x8*>(Kc + (i * 16 + krow) * 128 + koff) = kreg[i];
#pragma unroll
        for (int i = 0; i < 4; ++i)
            *reinterpret_cast<s16x8*>(Vc + (i * 32 + vrow) * 64 + voff) = vreg[i];
        if (kt < 31) load_tile(kv0 + 64);               // stays in flight across barrier
        asm volatile("s_waitcnt lgkmcnt(0)" ::: "memory");  // writes visible
        asm volatile("s_barrier" ::: "memory");             // NO vmcnt drain

        // P^T = K Q^T: sc[sub] covers kv-subtile sub*32, cols q
        f32x16 sc[2];
#pragma unroll
        for (int sub = 0; sub < 2; ++sub)
#pragma unroll
            for (int r = 0; r < 16; ++r) sc[sub][r] = 0.f;
        __builtin_amdgcn_s_setprio(1);
#pragma unroll
        for (int sub = 0; sub < 2; ++sub) {
            const int kr = sub * 32 + lq;
            const int ksw = kr & 7;
#pragma unroll
            for (int ks = 0; ks < 8; ++ks) {
                s16x8 kf = *reinterpret_cast<const s16x8*>(
                    Kc + kr * 128 + (((ks * 2 + hi2) ^ ksw) * 8));
                sc[sub] = __builtin_amdgcn_mfma_f32_32x32x16_bf16(kf, qf[ks], sc[sub], 0, 0, 0);
            }
        }
        __builtin_amdgcn_s_setprio(0);
        // scale + bias
#pragma unroll
        for (int sub = 0; sub < 2; ++sub)
#pragma unroll
            for (int r = 0; r < 16; ++r)
                sc[sub][r] = fmaf(sc[sub][r], scale2, bi[sub][r >> 2][r & 3]);
        // local row-max (for rare-rescale guard; off critical path)
        float mx = sc[0][0];
#pragma unroll
        for (int sub = 0; sub < 2; ++sub)
#pragma unroll
            for (int r = 0; r < 16; ++r) mx = fmaxf(mx, sc[sub][r]);
        // speculative exp2 with current m_run (likely stable at 0)
        float ss = 0.f;
#pragma unroll
        for (int sub = 0; sub < 2; ++sub)
#pragma unroll
            for (int r = 0; r < 16; ++r) {
                sc[sub][r] = fexp2(sc[sub][r] - m_run);
                ss += sc[sub][r];
            }
        mx = fmaxf(mx, __shfl_xor(mx, 32));
        if (__ballot(mx > m_run + 11.5417f) != 0ull) {  // rare: correct the speculation
            const float mnew = fmaxf(m_run, mx);
            const float alpha = fexp2(m_run - mnew);
            m_run = mnew;
            l_run *= alpha;
            ss *= alpha;
#pragma unroll
            for (int sub = 0; sub < 2; ++sub)
#pragma unroll
                for (int r = 0; r < 16; ++r) sc[sub][r] *= alpha;
#pragma unroll
            for (int dt = 0; dt < 4; ++dt)
#pragma unroll
                for (int r = 0; r < 16; ++r) o[dt][r] *= alpha;  // q lane-local
        }
        ss += __shfl_xor(ss, 32);
        l_run += ss;
        // P -> bf16 words: wvp[r4g][t] = pk(kv j=2t,2t+1) of 4-block r4g (kv=8*r4g+4*hi2)
        unsigned int wvp[8][2];
#pragma unroll
        for (int g = 0; g < 8; ++g) {
            const int sub = g >> 2, r4 = g & 3;
            asm("v_cvt_pk_bf16_f32 %0, %1, %2"
                : "=v"(wvp[g][0]) : "v"(sc[sub][r4 * 4 + 0]), "v"(sc[sub][r4 * 4 + 1]));
            asm("v_cvt_pk_bf16_f32 %0, %1, %2"
                : "=v"(wvp[g][1]) : "v"(sc[sub][r4 * 4 + 2]), "v"(sc[sub][r4 * 4 + 3]));
        }
        // O^T += V^T P^T  (A = V^T rows dv; B = P^T cols q, k = kv)
        __builtin_amdgcn_s_setprio(1);
#pragma unroll
        for (int ks = 0; ks < 4; ++ks) {
            u32x2 r0 = __builtin_amdgcn_permlane32_swap(wvp[2 * ks][0], wvp[2 * ks + 1][0], false, false);
            u32x2 r1 = __builtin_amdgcn_permlane32_swap(wvp[2 * ks][1], wvp[2 * ks + 1][1], false, false);
            union { unsigned int u[4]; s16x8 v; } pf;
            pf.u[0] = r0.x; pf.u[1] = r1.x; pf.u[2] = r0.y; pf.u[3] = r1.y;
#pragma unroll
            for (int dt = 0; dt < 4; ++dt) {
                const int dvr = dt * 32 + lq;
                s16x8 vf = *reinterpret_cast<const s16x8*>(
                    Vc + dvr * 64 + (((ks * 2 + hi2) ^ (dvr & 7)) * 8));
                o[dt] = __builtin_amdgcn_mfma_f32_32x32x16_bf16(vf, pf.v, o[dt], 0, 0, 0);
            }
        }
        __builtin_amdgcn_s_setprio(0);
    };

    load_tile(0);
    for (int kt2 = 0; kt2 < 16; ++kt2) {                // x2 unroll: static LDS bases
        body(2 * kt2,     &Ks[0][0], &Vs[0][0]);
        body(2 * kt2 + 1, &Ks[1][0], &Vs[1][0]);
    }
    // epilogue: Oo[s][h*128 + dv] = o / l; q = lq lane-local, dv = dt*32+8*r4+4*hi2+j
    const float inv = 1.f / l_run;
    const size_t obase = (size_t)(b * S + qt * 128 + wv_ * 32 + lq) * 2048 + h * 128;
#pragma unroll
    for (int dt = 0; dt < 4; ++dt)
#pragma unroll
        for (int r4 = 0; r4 < 4; ++r4) {
            union { s16x4 v4; __hip_bfloat16 hh[4]; } u;
#pragma unroll
            for (int j = 0; j < 4; ++j)
                u.hh[j] = __float2bfloat16(o[dt][r4 * 4 + j] * inv);
            *reinterpret_cast<s16x4*>(&Oo[obase + dt * 32 + r4 * 8 + hi2 * 4]) = u.v4;
        }
}

// ---------------- host launch ----------------
extern "C" void kernel_launch(void* const* d_in, const int* in_sizes, int n_in,
                              void* d_out, int out_size, void* d_ws, size_t ws_size,
                              hipStream_t stream) {
    const float* x  = (const float*)d_in[0];
    const int* mask = (const int*)d_in[1];
    const float* Wq = (const float*)d_in[2];
    const float* Wk = (const float*)d_in[3];
    const float* Wv = (const float*)d_in[4];
    const float* Wo = (const float*)d_in[5];
    float* out = (float*)d_out;

    char* ws = (char*)d_ws;
    size_t off = 0;
    auto alloc = [&](size_t bytes) -> void* {
        void* p = ws + off;
        off += (bytes + 255) & ~(size_t)255;
        return p;
    };
    __hip_bfloat16* xb     = (__hip_bfloat16*)alloc(4096ULL * 2048 * 2);   // 16 MB
    __hip_bfloat16* wqkv_t = (__hip_bfloat16*)alloc(3072ULL * 2048 * 2);   // 12 MB
    __hip_bfloat16* wo_t   = (__hip_bfloat16*)alloc(2048ULL * 2048 * 2);   // 8 MB
    __hip_bfloat16* qkvb   = (__hip_bfloat16*)alloc(4096ULL * 3072 * 2);   // 24 MB
    __hip_bfloat16* Kr     = (__hip_bfloat16*)alloc(2ULL * 4 * 2048 * 128 * 2);  // 4 MB
    __hip_bfloat16* Vt     = (__hip_bfloat16*)alloc(2ULL * 4 * 2048 * 128 * 2);  // 4 MB
    float*          cosT   = (float*)alloc(2048ULL * 64 * 4);
    float*          sinT   = (float*)alloc(2048ULL * 64 * 4);
    float*          maskb  = (float*)alloc(2ULL * 2048 * 4);
    __hip_bfloat16* attno  = (__hip_bfloat16*)alloc(4096ULL * 2048 * 2);   // 16 MB
    __hip_bfloat16* Qr    = xb;   // xb dead after QKV GEMM; Qr written after

    tables_prep<<<dim3(2064), dim3(64), 0, stream>>>(cosT, sinT, mask, maskb);
    cast_f32_bf16<<<dim3(8192), dim3(256), 0, stream>>>(x, xb, 2097152);
    transpose_cast_all<<<dim3(160, 64), dim3(32, 8), 0, stream>>>(Wq, Wk, Wv, Wo, wqkv_t, wo_t);

    // QKV: 256x192 tiles, 1-D grid 256 (NX=16, NY=16), bf16 output — 1 block/CU
    gemm256_bt<3, true><<<dim3(256), dim3(512), 0, stream>>>(xb, wqkv_t, qkvb, 4096, 3072, 2048, 16);
    rope_scatter<<<dim3(3, 4096), dim3(256), 0, stream>>>(qkvb, cosT, sinT, Qr, Kr);
    vt_transpose<<<dim3(64, 4, 8), dim3(32, 8), 0, stream>>>(qkvb, Vt);
    attn_kernel<<<dim3(512), dim3(256), 0, stream>>>(Qr, Kr, Vt, maskb, attno);
    // Wo: 128x256 tiles, 1-D grid 256 (NX=8, NY=32), fp32 output — compute-fed ratio
    gemm128x256_bt<<<dim3(256), dim3(512), 0, stream>>>(attno, wo_t, out, 4096, 2048, 2048);
}

// Round 18
// 216.612 us; speedup vs baseline: 1.0670x; 1.0670x over previous
//
#include <hip/hip_runtime.h>
#include <hip/hip_bf16.h>

typedef __attribute__((ext_vector_type(4))) float f32x4;
typedef __attribute__((ext_vector_type(16))) float f32x16;
typedef __attribute__((ext_vector_type(8))) short s16x8;
typedef __attribute__((ext_vector_type(4))) short s16x4;
typedef __attribute__((ext_vector_type(2))) unsigned int u32x2;

__device__ __forceinline__ float fexp2(float x) {   // 2^x
    float y; asm("v_exp_f32 %0, %1" : "=v"(y) : "v"(x)); return y;
}

// ---------------- RoPE tables + mask bias (merged prep) ----------------
__global__ void tables_prep(float* __restrict__ cosT, float* __restrict__ sinT,
                            const int* __restrict__ mask, float* __restrict__ mb) {
    const int bid = blockIdx.x;
    if (bid < 2048) {
        const int s = bid, j = threadIdx.x;             // j in [0,64)
        const float inv = exp2f(-(float)j * (13.287712379549449f / 64.f)); // 10000^(-j/64)
        const float f = (float)s * inv;
        cosT[s * 64 + j] = cosf(f);
        sinT[s * 64 + j] = sinf(f);
    } else {
        const int base = (bid - 2048) * 64 + threadIdx.x;   // 16 blocks x 64 thr
#pragma unroll
        for (int k = 0; k < 4; ++k)
            mb[base + k * 1024] = (mask[base + k * 1024] == 0) ? -1e30f : 0.f;
    }
}

// ---------------- cast fp32 -> bf16 (vectorized) ----------------
__global__ __launch_bounds__(256)
void cast_f32_bf16(const float* __restrict__ src, __hip_bfloat16* __restrict__ dst, int n4) {
    const int i = blockIdx.x * 256 + threadIdx.x;
    if (i < n4) {
        f32x4 v = *reinterpret_cast<const f32x4*>(src + (size_t)i * 4);
        union { s16x4 v4; __hip_bfloat16 h[4]; } u;
#pragma unroll
        for (int j = 0; j < 4; ++j) u.h[j] = __float2bfloat16(v[j]);
        *reinterpret_cast<s16x4*>(dst + (size_t)i * 4) = u.v4;
    }
}

// ---------------- fused weight transposes: Wq|Wk|Wv -> wqkv_t, Wo -> wo_t ----------------
__global__ __launch_bounds__(256)
void transpose_cast_all(const float* __restrict__ Wq, const float* __restrict__ Wk,
                        const float* __restrict__ Wv, const float* __restrict__ Wo,
                        __hip_bfloat16* __restrict__ wqkv_t, __hip_bfloat16* __restrict__ wo_t) {
    __shared__ __align__(16) float t[32][33];
    const int tx = threadIdx.x, ty = threadIdx.y;       // (32, 8)
    const int xseg = blockIdx.x;                        // 0..159
    const int r0 = blockIdx.y * 32;                     // source row base, R = 2048 always
    const float* src; __hip_bfloat16* dst; int C, c0;
    if (xseg < 64)      { src = Wq; dst = wqkv_t;                  C = 2048; c0 = xseg * 32; }
    else if (xseg < 80) { src = Wk; dst = wqkv_t + 2048ULL * 2048; C = 512;  c0 = (xseg - 64) * 32; }
    else if (xseg < 96) { src = Wv; dst = wqkv_t + 2560ULL * 2048; C = 512;  c0 = (xseg - 80) * 32; }
    else                { src = Wo; dst = wo_t;                    C = 2048; c0 = (xseg - 96) * 32; }
#pragma unroll
    for (int i = 0; i < 32; i += 8)
        t[ty + i][tx] = src[(size_t)(r0 + ty + i) * C + c0 + tx];
    __syncthreads();
#pragma unroll
    for (int i = 0; i < 32; i += 8)
        dst[(size_t)(c0 + ty + i) * 2048 + r0 + tx] = __float2bfloat16(t[tx][ty + i]);
}

// ---------------- V slice of bf16 qkv -> Vt[b][hh][d][s] (bit-copy transpose) ----------------
__global__ __launch_bounds__(256)
void vt_transpose(const __hip_bfloat16* __restrict__ qkv, __hip_bfloat16* __restrict__ Vt) {
    __shared__ unsigned short t[32][33];
    const int tx = threadIdx.x, ty = threadIdx.y;       // (32, 8)
    const int s0 = blockIdx.x * 32, d0 = blockIdx.y * 32;
    const int bh = blockIdx.z, b = bh >> 2, hh = bh & 3;
    const unsigned short* q = (const unsigned short*)qkv;
#pragma unroll
    for (int i = 0; i < 32; i += 8)
        t[ty + i][tx] = q[(size_t)(b * 2048 + s0 + ty + i) * 3072 + 2560 + hh * 128 + d0 + tx];
    __syncthreads();
#pragma unroll
    for (int i = 0; i < 32; i += 8)
        ((unsigned short*)Vt)[((size_t)(bh * 128) + d0 + ty + i) * 2048 + s0 + tx] = t[tx][ty + i];
}

// ---------------- 256-row-tile GEMM, counted-vmcnt 4-slot pipeline (T4) ----------
// NI = per-wave N fragments: 4 -> BN=256, 3 -> BN=192, 2 -> BN=128.
template<int NI, bool BF16OUT>
__global__ __launch_bounds__(512, 1)
void gemm256_bt(const __hip_bfloat16* __restrict__ A,
                const __hip_bfloat16* __restrict__ Bt,
                void* __restrict__ Cv, int M, int N, int K, int NX) {
    __shared__ __align__(16) __hip_bfloat16 sm[4][2][8192];
    const int tid = threadIdx.x;
    const int l = tid & 63, w = tid >> 6;               // 8 waves
    const int lo = l & 15, hi = l >> 4;
    const int wm = w >> 2, wn = w & 3;
    const int id = blockIdx.x, slot = id >> 3;
    const int by = (id & 7) * 2 + slot / NX;
    const int bx = slot % NX;
    const int row0 = by * 256;
    const int col0 = bx * (NI * 64);
    const int nk = K >> 5;

    f32x4 acc[8][NI];
#pragma unroll
    for (int mi = 0; mi < 8; ++mi)
#pragma unroll
        for (int ni = 0; ni < NI; ++ni) acc[mi][ni] = f32x4{0.f, 0.f, 0.f, 0.f};

    auto ldlds = [&](const __hip_bfloat16* gsrc, __hip_bfloat16* ldst) {
        __builtin_amdgcn_global_load_lds(
            (const __attribute__((address_space(1))) void*)gsrc,
            (__attribute__((address_space(3))) void*)ldst, 16, 0, 0);
    };
    auto stage = [&](int kt) {
        const int s = kt & 3, k0 = kt << 5;
#pragma unroll
        for (int i = 0; i < 2; ++i) {                   // A: 256 rows x 4 chunks
            const int c = i * 512 + tid;
            const int r = c >> 2, sw = ((c & 3) ^ ((r >> 1) & 3)) * 8;
            ldlds(A + (size_t)(row0 + r) * K + k0 + sw, &sm[s][0][c * 8]);
        }
        {                                               // B chunk set 0: 0..511
            const int c = tid;
            const int r = c >> 2, sw = ((c & 3) ^ ((r >> 1) & 3)) * 8;
            ldlds(Bt + (size_t)(col0 + r) * K + k0 + sw, &sm[s][1][c * 8]);
        }
        if constexpr (NI == 4) {                        // B chunks 512..1023
            const int c = 512 + tid;
            const int r = c >> 2, sw = ((c & 3) ^ ((r >> 1) & 3)) * 8;
            ldlds(Bt + (size_t)(col0 + r) * K + k0 + sw, &sm[s][1][c * 8]);
        } else if constexpr (NI == 3) {                 // B chunks 512..767 (waves 0-3)
            if (tid < 256) {
                const int c = 512 + tid;
                const int r = c >> 2, sw = ((c & 3) ^ ((r >> 1) & 3)) * 8;
                ldlds(Bt + (size_t)(col0 + r) * K + k0 + sw, &sm[s][1][c * 8]);
            }
        }
    };

    stage(0); stage(1); stage(2);                       // 3 tiles ahead
    for (int kt = 0; kt < nk; ++kt) {
        const int s = kt & 3;
        if (kt < nk - 2) {
            if constexpr (NI == 4)      asm volatile("s_waitcnt vmcnt(8)" ::: "memory");
            else if constexpr (NI == 2) asm volatile("s_waitcnt vmcnt(6)" ::: "memory");
            else { if (tid < 256) asm volatile("s_waitcnt vmcnt(8)" ::: "memory");
                   else           asm volatile("s_waitcnt vmcnt(6)" ::: "memory"); }
        } else if (kt == nk - 2) {
            if constexpr (NI == 4)      asm volatile("s_waitcnt vmcnt(4)" ::: "memory");
            else if constexpr (NI == 2) asm volatile("s_waitcnt vmcnt(3)" ::: "memory");
            else { if (tid < 256) asm volatile("s_waitcnt vmcnt(4)" ::: "memory");
                   else           asm volatile("s_waitcnt vmcnt(3)" ::: "memory"); }
        } else {
            asm volatile("s_waitcnt vmcnt(0)" ::: "memory");
        }
        asm volatile("s_waitcnt lgkmcnt(0)" ::: "memory");  // slot reads of kt-1 done
        asm volatile("s_barrier" ::: "memory");             // no compiler drain added
        if (kt + 3 < nk) stage(kt + 3);                     // into slot (kt-1)&3: safe

        s16x8 af[8], bf[NI];
        const int rsw = ((lo >> 1) & 3);                // f(row), row base %16 == 0
#pragma unroll
        for (int mi = 0; mi < 8; ++mi)
            af[mi] = *reinterpret_cast<const s16x8*>(
                &sm[s][0][(wm * 128 + mi * 16 + lo) * 32 + ((hi ^ rsw) * 8)]);
#pragma unroll
        for (int ni = 0; ni < NI; ++ni)
            bf[ni] = *reinterpret_cast<const s16x8*>(
                &sm[s][1][(wn * NI * 16 + ni * 16 + lo) * 32 + ((hi ^ rsw) * 8)]);
        __builtin_amdgcn_s_setprio(1);
#pragma unroll
        for (int mi = 0; mi < 8; ++mi)
#pragma unroll
            for (int ni = 0; ni < NI; ++ni)
                acc[mi][ni] = __builtin_amdgcn_mfma_f32_16x16x32_bf16(af[mi], bf[ni], acc[mi][ni], 0, 0, 0);
        __builtin_amdgcn_s_setprio(0);
    }
    const int rbase = row0 + wm * 128 + hi * 4;
    const int cbase = col0 + wn * NI * 16 + lo;
    if constexpr (BF16OUT) {
        __hip_bfloat16* C = (__hip_bfloat16*)Cv;
#pragma unroll
        for (int mi = 0; mi < 8; ++mi)
#pragma unroll
            for (int ni = 0; ni < NI; ++ni)
#pragma unroll
                for (int r = 0; r < 4; ++r)
                    C[(size_t)(rbase + mi * 16 + r) * N + cbase + ni * 16] =
                        __float2bfloat16(acc[mi][ni][r]);
    } else {
        float* C = (float*)Cv;
#pragma unroll
        for (int mi = 0; mi < 8; ++mi)
#pragma unroll
            for (int ni = 0; ni < NI; ++ni)
#pragma unroll
                for (int r = 0; r < 4; ++r)
                    C[(size_t)(rbase + mi * 16 + r) * N + cbase + ni * 16] = acc[mi][ni][r];
    }
}

// ---------------- RoPE + scatter (Q/K only, bf16 in/out, vectorized) ----------------
__global__ __launch_bounds__(256)
void rope_scatter(const __hip_bfloat16* __restrict__ qkv,
                  const float* __restrict__ cosT, const float* __restrict__ sinT,
                  __hip_bfloat16* __restrict__ Qr, __hip_bfloat16* __restrict__ Kr) {
    const int m = blockIdx.y;                           // token row, 0..4095
    const int col4 = blockIdx.x * 256 + threadIdx.x;    // 0..639
    if (col4 >= 640) return;
    const int col = col4 * 4;
    const int b = m >> 11, s = m & 2047;
    const int d = col & 127;                            // 4-aligned
    const int j = d & 63;
    union { s16x4 v4; __hip_bfloat16 h[4]; } vv, pp, u;
    vv.v4 = *reinterpret_cast<const s16x4*>(qkv + (size_t)m * 3072 + col);
    pp.v4 = *reinterpret_cast<const s16x4*>(qkv + (size_t)m * 3072 + (col ^ 64));
    const f32x4 c4 = *reinterpret_cast<const f32x4*>(cosT + s * 64 + j);
    const f32x4 s4 = *reinterpret_cast<const f32x4*>(sinT + s * 64 + j);
    const float sgn = (d < 64) ? -1.f : 1.f;
#pragma unroll
    for (int i = 0; i < 4; ++i)
        u.h[i] = __float2bfloat16(__bfloat162float(vv.h[i]) * c4[i] +
                                  sgn * __bfloat162float(pp.h[i]) * s4[i]);
    if (col < 2048) {
        const int hh = col >> 7;
        *reinterpret_cast<s16x4*>(&Qr[((size_t)(b * 16 + hh) * 2048 + s) * 128 + d]) = u.v4;
    } else {
        const int hh = (col - 2048) >> 7;
        *reinterpret_cast<s16x4*>(&Kr[((size_t)(b * 4 + hh) * 2048 + s) * 128 + d]) = u.v4;
    }
}

// ---------------- flash attention: 4 waves x 32 q-rows, 32x32 MFMA, LDS-free P ----------------
// r14-exact (proven 87.7 us): 2 blocks/CU, 8 waves/CU is the measured optimum of
// the {LDS-port-traffic x latency-hiding} trade. XCD-chunked KV slices L2-resident.
__global__ __launch_bounds__(256, 2)
void attn_kernel(const __hip_bfloat16* __restrict__ Qr,
                 const __hip_bfloat16* __restrict__ Kr,
                 const __hip_bfloat16* __restrict__ Vt,
                 const float* __restrict__ maskb,
                 __hip_bfloat16* __restrict__ Oo) {
    const int S = 2048;
    const int id = blockIdx.x;                          // 0..511
    const int v = (id & 7) * 64 + (id >> 3);            // XCD-chunked, bijective
    const int qt = v & 15;                              // 0..15 (128 q-rows/block)
    const int bh = v >> 4;                              // 0..31
    const int b = bh >> 4, h = bh & 15, kvh = h >> 2;
    const int tid = threadIdx.x;
    const int l = tid & 63, wv_ = tid >> 6;             // 4 waves
    const int lq = l & 31, hi2 = l >> 5;
    __shared__ __align__(16) __hip_bfloat16 Ks[2][64 * 128];   // [kv][d], chunk-swizzled
    __shared__ __align__(16) __hip_bfloat16 Vs[2][128 * 64];   // [d][kv], chunk-swizzled

    const __hip_bfloat16* Qb = Qr + (size_t)(b * 16 + h) * S * 128;
    const __hip_bfloat16* Kb = Kr + (size_t)(b * 4 + kvh) * S * 128;
    const __hip_bfloat16* Vb = Vt + (size_t)(b * 4 + kvh) * 128 * S;
    const float* mrow = maskb + b * S;

    // Q fragments (B-operand): col q = lq, k = d = ks*16 + hi2*8 + j
    const int qrow = qt * 128 + wv_ * 32 + lq;
    s16x8 qf[8];
#pragma unroll
    for (int ks = 0; ks < 8; ++ks)
        qf[ks] = *reinterpret_cast<const s16x8*>(Qb + (size_t)qrow * 128 + ks * 16 + hi2 * 8);

    float m_run = 0.f, l_run = 0.f;                     // exp2-domain; row q = lq lane-local
    f32x16 o[4];                                        // O^T[dv = dt*32+...][q = lq]
#pragma unroll
    for (int dt = 0; dt < 4; ++dt)
#pragma unroll
        for (int r = 0; r < 16; ++r) o[dt][r] = 0.f;
    const float scale2 = 0.12751682f;                   // 1/sqrt(128) * log2(e)

    // staging: 256 threads; K 64x16 chunks, V 128x8 chunks, 4 each
    const int krow = tid >> 4, kc8 = tid & 15;          // rows i*16+krow
    const int koff = (kc8 ^ (krow & 7)) * 8;
    const int vrow = tid >> 3, vc8 = tid & 7;           // rows i*32+vrow
    const int voff = (vc8 ^ (vrow & 7)) * 8;

    s16x8 kreg[4], vreg[4];
    auto load_tile = [&](int kv0) {
#pragma unroll
        for (int i = 0; i < 4; ++i)
            kreg[i] = *reinterpret_cast<const s16x8*>(
                Kb + (size_t)(kv0 + i * 16 + krow) * 128 + kc8 * 8);
#pragma unroll
        for (int i = 0; i < 4; ++i)
            vreg[i] = *reinterpret_cast<const s16x8*>(
                Vb + (size_t)(i * 32 + vrow) * S + kv0 + vc8 * 8);
    };

    auto body = [&](int kt, __hip_bfloat16* Kc, __hip_bfloat16* Vc) {
        const int kv0 = kt * 64;
        // mask bias: kv = kv0 + 32*sub + 8*r4 + 4*hi2 + j
        f32x4 bi[2][4];
#pragma unroll
        for (int sub = 0; sub < 2; ++sub)
#pragma unroll
            for (int r4 = 0; r4 < 4; ++r4)
                bi[sub][r4] = *reinterpret_cast<const f32x4*>(
                    mrow + kv0 + sub * 32 + r4 * 8 + hi2 * 4);
#pragma unroll
        for (int i = 0; i < 4; ++i)
            *reinterpret_cast<s16x8*>(Kc + (i * 16 + krow) * 128 + koff) = kreg[i];
#pragma unroll
        for (int i = 0; i < 4; ++i)
            *reinterpret_cast<s16x8*>(Vc + (i * 32 + vrow) * 64 + voff) = vreg[i];
        if (kt < 31) load_tile(kv0 + 64);               // stays in flight across barrier
        asm volatile("s_waitcnt lgkmcnt(0)" ::: "memory");  // writes visible
        asm volatile("s_barrier" ::: "memory");             // NO vmcnt drain

        // P^T = K Q^T: sc[sub] covers kv-subtile sub*32, cols q
        f32x16 sc[2];
#pragma unroll
        for (int sub = 0; sub < 2; ++sub)
#pragma unroll
            for (int r = 0; r < 16; ++r) sc[sub][r] = 0.f;
        __builtin_amdgcn_s_setprio(1);
#pragma unroll
        for (int sub = 0; sub < 2; ++sub) {
            const int kr = sub * 32 + lq;
            const int ksw = kr & 7;
#pragma unroll
            for (int ks = 0; ks < 8; ++ks) {
                s16x8 kf = *reinterpret_cast<const s16x8*>(
                    Kc + kr * 128 + (((ks * 2 + hi2) ^ ksw) * 8));
                sc[sub] = __builtin_amdgcn_mfma_f32_32x32x16_bf16(kf, qf[ks], sc[sub], 0, 0, 0);
            }
        }
        __builtin_amdgcn_s_setprio(0);
        // scale + bias
#pragma unroll
        for (int sub = 0; sub < 2; ++sub)
#pragma unroll
            for (int r = 0; r < 16; ++r)
                sc[sub][r] = fmaf(sc[sub][r], scale2, bi[sub][r >> 2][r & 3]);
        // local row-max (for rare-rescale guard; off critical path)
        float mx = sc[0][0];
#pragma unroll
        for (int sub = 0; sub < 2; ++sub)
#pragma unroll
            for (int r = 0; r < 16; ++r) mx = fmaxf(mx, sc[sub][r]);
        // speculative exp2 with current m_run (likely stable at 0)
        float ss = 0.f;
#pragma unroll
        for (int sub = 0; sub < 2; ++sub)
#pragma unroll
            for (int r = 0; r < 16; ++r) {
                sc[sub][r] = fexp2(sc[sub][r] - m_run);
                ss += sc[sub][r];
            }
        mx = fmaxf(mx, __shfl_xor(mx, 32));
        if (__ballot(mx > m_run + 11.5417f) != 0ull) {  // rare: correct the speculation
            const float mnew = fmaxf(m_run, mx);
            const float alpha = fexp2(m_run - mnew);
            m_run = mnew;
            l_run *= alpha;
            ss *= alpha;
#pragma unroll
            for (int sub = 0; sub < 2; ++sub)
#pragma unroll
                for (int r = 0; r < 16; ++r) sc[sub][r] *= alpha;
#pragma unroll
            for (int dt = 0; dt < 4; ++dt)
#pragma unroll
                for (int r = 0; r < 16; ++r) o[dt][r] *= alpha;  // q lane-local
        }
        ss += __shfl_xor(ss, 32);
        l_run += ss;
        // P -> bf16 words: wvp[r4g][t] = pk(kv j=2t,2t+1) of 4-block r4g (kv=8*r4g+4*hi2)
        unsigned int wvp[8][2];
#pragma unroll
        for (int g = 0; g < 8; ++g) {
            const int sub = g >> 2, r4 = g & 3;
            asm("v_cvt_pk_bf16_f32 %0, %1, %2"
                : "=v"(wvp[g][0]) : "v"(sc[sub][r4 * 4 + 0]), "v"(sc[sub][r4 * 4 + 1]));
            asm("v_cvt_pk_bf16_f32 %0, %1, %2"
                : "=v"(wvp[g][1]) : "v"(sc[sub][r4 * 4 + 2]), "v"(sc[sub][r4 * 4 + 3]));
        }
        // O^T += V^T P^T  (A = V^T rows dv; B = P^T cols q, k = kv)
        __builtin_amdgcn_s_setprio(1);
#pragma unroll
        for (int ks = 0; ks < 4; ++ks) {
            u32x2 r0 = __builtin_amdgcn_permlane32_swap(wvp[2 * ks][0], wvp[2 * ks + 1][0], false, false);
            u32x2 r1 = __builtin_amdgcn_permlane32_swap(wvp[2 * ks][1], wvp[2 * ks + 1][1], false, false);
            union { unsigned int u[4]; s16x8 v; } pf;
            pf.u[0] = r0.x; pf.u[1] = r1.x; pf.u[2] = r0.y; pf.u[3] = r1.y;
#pragma unroll
            for (int dt = 0; dt < 4; ++dt) {
                const int dvr = dt * 32 + lq;
                s16x8 vf = *reinterpret_cast<const s16x8*>(
                    Vc + dvr * 64 + (((ks * 2 + hi2) ^ (dvr & 7)) * 8));
                o[dt] = __builtin_amdgcn_mfma_f32_32x32x16_bf16(vf, pf.v, o[dt], 0, 0, 0);
            }
        }
        __builtin_amdgcn_s_setprio(0);
    };

    load_tile(0);
    for (int kt2 = 0; kt2 < 16; ++kt2) {                // x2 unroll: static LDS bases
        body(2 * kt2,     &Ks[0][0], &Vs[0][0]);
        body(2 * kt2 + 1, &Ks[1][0], &Vs[1][0]);
    }
    // epilogue: Oo[s][h*128 + dv] = o / l; q = lq lane-local, dv = dt*32+8*r4+4*hi2+j
    const float inv = 1.f / l_run;
    const size_t obase = (size_t)(b * S + qt * 128 + wv_ * 32 + lq) * 2048 + h * 128;
#pragma unroll
    for (int dt = 0; dt < 4; ++dt)
#pragma unroll
        for (int r4 = 0; r4 < 4; ++r4) {
            union { s16x4 v4; __hip_bfloat16 hh[4]; } u;
#pragma unroll
            for (int j = 0; j < 4; ++j)
                u.hh[j] = __float2bfloat16(o[dt][r4 * 4 + j] * inv);
            *reinterpret_cast<s16x4*>(&Oo[obase + dt * 32 + r4 * 8 + hi2 * 4]) = u.v4;
        }
}

// ---------------- host launch ----------------
extern "C" void kernel_launch(void* const* d_in, const int* in_sizes, int n_in,
                              void* d_out, int out_size, void* d_ws, size_t ws_size,
                              hipStream_t stream) {
    const float* x  = (const float*)d_in[0];
    const int* mask = (const int*)d_in[1];
    const float* Wq = (const float*)d_in[2];
    const float* Wk = (const float*)d_in[3];
    const float* Wv = (const float*)d_in[4];
    const float* Wo = (const float*)d_in[5];
    float* out = (float*)d_out;

    char* ws = (char*)d_ws;
    size_t off = 0;
    auto alloc = [&](size_t bytes) -> void* {
        void* p = ws + off;
        off += (bytes + 255) & ~(size_t)255;
        return p;
    };
    __hip_bfloat16* xb     = (__hip_bfloat16*)alloc(4096ULL * 2048 * 2);   // 16 MB
    __hip_bfloat16* wqkv_t = (__hip_bfloat16*)alloc(3072ULL * 2048 * 2);   // 12 MB
    __hip_bfloat16* wo_t   = (__hip_bfloat16*)alloc(2048ULL * 2048 * 2);   // 8 MB
    __hip_bfloat16* qkvb   = (__hip_bfloat16*)alloc(4096ULL * 3072 * 2);   // 24 MB
    __hip_bfloat16* Kr     = (__hip_bfloat16*)alloc(2ULL * 4 * 2048 * 128 * 2);  // 4 MB
    __hip_bfloat16* Vt     = (__hip_bfloat16*)alloc(2ULL * 4 * 2048 * 128 * 2);  // 4 MB
    float*          cosT   = (float*)alloc(2048ULL * 64 * 4);
    float*          sinT   = (float*)alloc(2048ULL * 64 * 4);
    float*          maskb  = (float*)alloc(2ULL * 2048 * 4);
    __hip_bfloat16* attno  = (__hip_bfloat16*)alloc(4096ULL * 2048 * 2);   // 16 MB
    __hip_bfloat16* Qr    = xb;   // xb dead after QKV GEMM; Qr written after

    tables_prep<<<dim3(2064), dim3(64), 0, stream>>>(cosT, sinT, mask, maskb);
    cast_f32_bf16<<<dim3(8192), dim3(256), 0, stream>>>(x, xb, 2097152);
    transpose_cast_all<<<dim3(160, 64), dim3(32, 8), 0, stream>>>(Wq, Wk, Wv, Wo, wqkv_t, wo_t);

    // QKV: 256x192 tiles, 1-D grid 256 (NX=16, NY=16), bf16 output — 1 block/CU
    gemm256_bt<3, true><<<dim3(256), dim3(512), 0, stream>>>(xb, wqkv_t, qkvb, 4096, 3072, 2048, 16);
    rope_scatter<<<dim3(3, 4096), dim3(256), 0, stream>>>(qkvb, cosT, sinT, Qr, Kr);
    vt_transpose<<<dim3(64, 4, 8), dim3(32, 8), 0, stream>>>(qkvb, Vt);
    attn_kernel<<<dim3(512), dim3(256), 0, stream>>>(Qr, Kr, Vt, maskb, attno);
    // Wo: 256x128 tiles, 1-D grid 256 (NX=16, NY=16), fp32 output
    gemm256_bt<2, false><<<dim3(256), dim3(512), 0, stream>>>(attno, wo_t, out, 4096, 2048, 2048, 16);
}

// Round 19
// 211.296 us; speedup vs baseline: 1.0938x; 1.0252x over previous
//
#include <hip/hip_runtime.h>
#include <hip/hip_bf16.h>

typedef __attribute__((ext_vector_type(4))) float f32x4;
typedef __attribute__((ext_vector_type(16))) float f32x16;
typedef __attribute__((ext_vector_type(8))) short s16x8;
typedef __attribute__((ext_vector_type(4))) short s16x4;
typedef __attribute__((ext_vector_type(2))) unsigned int u32x2;

__device__ __forceinline__ float fexp2(float x) {   // 2^x
    float y; asm("v_exp_f32 %0, %1" : "=v"(y) : "v"(x)); return y;
}

// ---------------- RoPE tables (TRANSPOSED [j][s]) + mask bias ----------------
__global__ void tables_prep(float* __restrict__ cosT2, float* __restrict__ sinT2,
                            const int* __restrict__ mask, float* __restrict__ mb) {
    const int bid = blockIdx.x;
    if (bid < 64) {                                     // j = bid; coalesced along s
        const int j = bid;
        const float inv = exp2f(-(float)j * (13.287712379549449f / 64.f)); // 10000^(-j/64)
#pragma unroll
        for (int k = 0; k < 8; ++k) {
            const int s = k * 256 + threadIdx.x;
            const float f = (float)s * inv;
            cosT2[j * 2048 + s] = cosf(f);
            sinT2[j * 2048 + s] = sinf(f);
        }
    } else {
        const int idx = (bid - 64) * 256 + threadIdx.x; // 16 blocks cover 4096
        mb[idx] = (mask[idx] == 0) ? -1e30f : 0.f;
    }
}

// ---------------- cast fp32 -> bf16 (vectorized) ----------------
__global__ __launch_bounds__(256)
void cast_f32_bf16(const float* __restrict__ src, __hip_bfloat16* __restrict__ dst, int n4) {
    const int i = blockIdx.x * 256 + threadIdx.x;
    if (i < n4) {
        f32x4 v = *reinterpret_cast<const f32x4*>(src + (size_t)i * 4);
        union { s16x4 v4; __hip_bfloat16 h[4]; } u;
#pragma unroll
        for (int j = 0; j < 4; ++j) u.h[j] = __float2bfloat16(v[j]);
        *reinterpret_cast<s16x4*>(dst + (size_t)i * 4) = u.v4;
    }
}

// ---------------- fused weight transposes: Wq|Wk|Wv -> wqkv_t, Wo -> wo_t ----------------
// Q and K rows are PERMUTED within each 128-row head: row p holds original column
// d(p) = 16*(p>>5) + (p&15) + 64*((p>>4)&1), i.e. p(dd) = (dd&15) + 32*((dd>>4)&3)
// + 16*(dd>>6). This puts each RoPE pair (d, d+64) exactly 16 GEMM-output columns
// apart -> same lane, adjacent ni fragments in the fused epilogue.
__global__ __launch_bounds__(256)
void transpose_cast_all(const float* __restrict__ Wq, const float* __restrict__ Wk,
                        const float* __restrict__ Wv, const float* __restrict__ Wo,
                        __hip_bfloat16* __restrict__ wqkv_t, __hip_bfloat16* __restrict__ wo_t) {
    __shared__ __align__(16) float t[32][33];
    const int tx = threadIdx.x, ty = threadIdx.y;       // (32, 8)
    const int xseg = blockIdx.x;                        // 0..159
    const int r0 = blockIdx.y * 32;                     // source row base, R = 2048 always
    const float* src; __hip_bfloat16* dst; int C, c0; bool perm;
    if (xseg < 64)      { src = Wq; dst = wqkv_t;                  C = 2048; c0 = xseg * 32;        perm = true; }
    else if (xseg < 80) { src = Wk; dst = wqkv_t + 2048ULL * 2048; C = 512;  c0 = (xseg - 64) * 32; perm = true; }
    else if (xseg < 96) { src = Wv; dst = wqkv_t + 2560ULL * 2048; C = 512;  c0 = (xseg - 80) * 32; perm = false; }
    else                { src = Wo; dst = wo_t;                    C = 2048; c0 = (xseg - 96) * 32; perm = false; }
#pragma unroll
    for (int i = 0; i < 32; i += 8)
        t[ty + i][tx] = src[(size_t)(r0 + ty + i) * C + c0 + tx];
    __syncthreads();
#pragma unroll
    for (int i = 0; i < 32; i += 8) {
        int row = c0 + ty + i;                          // source column index
        if (perm)
            row = (row & ~127) + (row & 15) + 32 * ((row >> 4) & 3) + 16 * ((row >> 6) & 1);
        dst[(size_t)row * 2048 + r0 + tx] = __float2bfloat16(t[tx][ty + i]);
    }
}

// ---------------- fused QKV GEMM: 256x256 tiles + RoPE/scatter epilogue ----------
// K-loop identical to the proven counted-vmcnt 4-slot pipeline (NI=4).
// Epilogue: bx 0..7 -> Q (RoPE, permuted cols), bx 8,9 -> K (RoPE), bx 10,11 -> V
// (transpose-scatter to Vt[d][s]). RoPE partner = acc[mi][ni^1][r] (same lane);
// pair shares j -> one f32x4 cos/sin load (transposed tables) per (mi, ni-pair).
__global__ __launch_bounds__(512, 1)
void gemm_qkv_fused(const __hip_bfloat16* __restrict__ A,
                    const __hip_bfloat16* __restrict__ Bt,
                    const float* __restrict__ cosT2, const float* __restrict__ sinT2,
                    __hip_bfloat16* __restrict__ Qr, __hip_bfloat16* __restrict__ Kr,
                    __hip_bfloat16* __restrict__ Vt, int K) {
    __shared__ __align__(16) __hip_bfloat16 sm[4][2][8192];
    const int tid = threadIdx.x;
    const int l = tid & 63, w = tid >> 6;               // 8 waves
    const int lo = l & 15, hi = l >> 4;
    const int wm = w >> 2, wn = w & 3;
    const int id = blockIdx.x, slot = id >> 3;          // grid 192, NX=12
    const int by = (id & 7) * 2 + slot / 12;
    const int bx = slot % 12;
    const int row0 = by * 256;
    const int col0 = bx * 256;
    const int nk = K >> 5;

    f32x4 acc[8][4];
#pragma unroll
    for (int mi = 0; mi < 8; ++mi)
#pragma unroll
        for (int ni = 0; ni < 4; ++ni) acc[mi][ni] = f32x4{0.f, 0.f, 0.f, 0.f};

    auto ldlds = [&](const __hip_bfloat16* gsrc, __hip_bfloat16* ldst) {
        __builtin_amdgcn_global_load_lds(
            (const __attribute__((address_space(1))) void*)gsrc,
            (__attribute__((address_space(3))) void*)ldst, 16, 0, 0);
    };
    auto stage = [&](int kt) {
        const int s = kt & 3, k0 = kt << 5;
#pragma unroll
        for (int i = 0; i < 2; ++i) {                   // A: 256 rows x 4 chunks
            const int c = i * 512 + tid;
            const int r = c >> 2, sw = ((c & 3) ^ ((r >> 1) & 3)) * 8;
            ldlds(A + (size_t)(row0 + r) * K + k0 + sw, &sm[s][0][c * 8]);
        }
#pragma unroll
        for (int i = 0; i < 2; ++i) {                   // B: 256 rows x 4 chunks
            const int c = i * 512 + tid;
            const int r = c >> 2, sw = ((c & 3) ^ ((r >> 1) & 3)) * 8;
            ldlds(Bt + (size_t)(col0 + r) * K + k0 + sw, &sm[s][1][c * 8]);
        }
    };

    stage(0); stage(1); stage(2);                       // 3 tiles ahead
    for (int kt = 0; kt < nk; ++kt) {
        const int s = kt & 3;
        if (kt < nk - 2)       asm volatile("s_waitcnt vmcnt(8)" ::: "memory");
        else if (kt == nk - 2) asm volatile("s_waitcnt vmcnt(4)" ::: "memory");
        else                   asm volatile("s_waitcnt vmcnt(0)" ::: "memory");
        asm volatile("s_waitcnt lgkmcnt(0)" ::: "memory");  // slot reads of kt-1 done
        asm volatile("s_barrier" ::: "memory");             // no compiler drain added
        if (kt + 3 < nk) stage(kt + 3);                     // into slot (kt-1)&3: safe

        s16x8 af[8], bf[4];
        const int rsw = ((lo >> 1) & 3);                // f(row), row base %16 == 0
#pragma unroll
        for (int mi = 0; mi < 8; ++mi)
            af[mi] = *reinterpret_cast<const s16x8*>(
                &sm[s][0][(wm * 128 + mi * 16 + lo) * 32 + ((hi ^ rsw) * 8)]);
#pragma unroll
        for (int ni = 0; ni < 4; ++ni)
            bf[ni] = *reinterpret_cast<const s16x8*>(
                &sm[s][1][(wn * 64 + ni * 16 + lo) * 32 + ((hi ^ rsw) * 8)]);
        __builtin_amdgcn_s_setprio(1);
#pragma unroll
        for (int mi = 0; mi < 8; ++mi)
#pragma unroll
            for (int ni = 0; ni < 4; ++ni)
                acc[mi][ni] = __builtin_amdgcn_mfma_f32_16x16x32_bf16(af[mi], bf[ni], acc[mi][ni], 0, 0, 0);
        __builtin_amdgcn_s_setprio(0);
    }

    const int rbase = row0 + wm * 128 + hi * 4;
    if (bx < 10) {
        // ---- Q or K block: RoPE in permuted-column space ----
        const int cw = col0 + wn * 64;                  // wave's 64-col block base
        const bool isQ = (bx < 8);
        const int head = (isQ ? cw : cw - 2048) >> 7;
        __hip_bfloat16* dst = isQ ? (Qr + ((size_t)head * 2048) * 128)
                                  : (Kr + ((size_t)head * 2048) * 128);
        // per-batch stride: Qr batch = 16 heads, Kr batch = 4 heads
        const size_t bstride = (isQ ? 16ull : 4ull) * 2048 * 128;
        const int jbase = 32 * (wn & 1) + lo;           // j = jbase + 16*np
#pragma unroll
        for (int mi = 0; mi < 8; ++mi) {
            const int tok = rbase + mi * 16;
            const int b = tok >> 11, s0 = tok & 2047;
            __hip_bfloat16* drow = dst + b * bstride + (size_t)s0 * 128;
#pragma unroll
            for (int np = 0; np < 2; ++np) {
                const int j = jbase + 16 * np;
                const f32x4 c4 = *reinterpret_cast<const f32x4*>(cosT2 + j * 2048 + s0);
                const f32x4 s4 = *reinterpret_cast<const f32x4*>(sinT2 + j * 2048 + s0);
                const int ni0 = 2 * np, ni1 = 2 * np + 1;
                const int dd0 = j;                      // h=0: d = j
#pragma unroll
                for (int r = 0; r < 4; ++r) {
                    const float v0 = acc[mi][ni0][r], v1 = acc[mi][ni1][r];
                    drow[(size_t)r * 128 + dd0]      = __float2bfloat16(v0 * c4[r] - v1 * s4[r]);
                    drow[(size_t)r * 128 + dd0 + 64] = __float2bfloat16(v1 * c4[r] + v0 * s4[r]);
                }
            }
        }
    } else {
        // ---- V block: transpose-scatter to Vt[b][hh][d][s], s packed via r ----
        const int cw = col0 + wn * 64 - 2560;           // 0..511
        const int hh = cw >> 7;
#pragma unroll
        for (int mi = 0; mi < 8; ++mi) {
            const int tok = rbase + mi * 16;
            const int b = tok >> 11, s0 = tok & 2047;
#pragma unroll
            for (int ni = 0; ni < 4; ++ni) {
                const int dd = (cw & 127) + ni * 16 + lo;
                union { s16x4 v4; __hip_bfloat16 h[4]; } u;
#pragma unroll
                for (int r = 0; r < 4; ++r) u.h[r] = __float2bfloat16(acc[mi][ni][r]);
                *reinterpret_cast<s16x4*>(
                    &Vt[((size_t)(b * 4 + hh) * 128 + dd) * 2048 + s0]) = u.v4;
            }
        }
    }
}

// ---------------- 256-row-tile GEMM (Wo), counted-vmcnt 4-slot pipeline ----------
template<int NI, bool BF16OUT>
__global__ __launch_bounds__(512, 1)
void gemm256_bt(const __hip_bfloat16* __restrict__ A,
                const __hip_bfloat16* __restrict__ Bt,
                void* __restrict__ Cv, int M, int N, int K, int NX) {
    __shared__ __align__(16) __hip_bfloat16 sm[4][2][8192];
    const int tid = threadIdx.x;
    const int l = tid & 63, w = tid >> 6;               // 8 waves
    const int lo = l & 15, hi = l >> 4;
    const int wm = w >> 2, wn = w & 3;
    const int id = blockIdx.x, slot = id >> 3;
    const int by = (id & 7) * 2 + slot / NX;
    const int bx = slot % NX;
    const int row0 = by * 256;
    const int col0 = bx * (NI * 64);
    const int nk = K >> 5;

    f32x4 acc[8][NI];
#pragma unroll
    for (int mi = 0; mi < 8; ++mi)
#pragma unroll
        for (int ni = 0; ni < NI; ++ni) acc[mi][ni] = f32x4{0.f, 0.f, 0.f, 0.f};

    auto ldlds = [&](const __hip_bfloat16* gsrc, __hip_bfloat16* ldst) {
        __builtin_amdgcn_global_load_lds(
            (const __attribute__((address_space(1))) void*)gsrc,
            (__attribute__((address_space(3))) void*)ldst, 16, 0, 0);
    };
    auto stage = [&](int kt) {
        const int s = kt & 3, k0 = kt << 5;
#pragma unroll
        for (int i = 0; i < 2; ++i) {                   // A: 256 rows x 4 chunks
            const int c = i * 512 + tid;
            const int r = c >> 2, sw = ((c & 3) ^ ((r >> 1) & 3)) * 8;
            ldlds(A + (size_t)(row0 + r) * K + k0 + sw, &sm[s][0][c * 8]);
        }
        {                                               // B chunk set 0: 0..511
            const int c = tid;
            const int r = c >> 2, sw = ((c & 3) ^ ((r >> 1) & 3)) * 8;
            ldlds(Bt + (size_t)(col0 + r) * K + k0 + sw, &sm[s][1][c * 8]);
        }
        if constexpr (NI == 4) {
            const int c = 512 + tid;
            const int r = c >> 2, sw = ((c & 3) ^ ((r >> 1) & 3)) * 8;
            ldlds(Bt + (size_t)(col0 + r) * K + k0 + sw, &sm[s][1][c * 8]);
        }
    };

    stage(0); stage(1); stage(2);                       // 3 tiles ahead
    for (int kt = 0; kt < nk; ++kt) {
        const int s = kt & 3;
        if (kt < nk - 2) {
            if constexpr (NI == 4) asm volatile("s_waitcnt vmcnt(8)" ::: "memory");
            else                   asm volatile("s_waitcnt vmcnt(6)" ::: "memory");
        } else if (kt == nk - 2) {
            if constexpr (NI == 4) asm volatile("s_waitcnt vmcnt(4)" ::: "memory");
            else                   asm volatile("s_waitcnt vmcnt(3)" ::: "memory");
        } else {
            asm volatile("s_waitcnt vmcnt(0)" ::: "memory");
        }
        asm volatile("s_waitcnt lgkmcnt(0)" ::: "memory");  // slot reads of kt-1 done
        asm volatile("s_barrier" ::: "memory");             // no compiler drain added
        if (kt + 3 < nk) stage(kt + 3);                     // into slot (kt-1)&3: safe

        s16x8 af[8], bf[NI];
        const int rsw = ((lo >> 1) & 3);                // f(row), row base %16 == 0
#pragma unroll
        for (int mi = 0; mi < 8; ++mi)
            af[mi] = *reinterpret_cast<const s16x8*>(
                &sm[s][0][(wm * 128 + mi * 16 + lo) * 32 + ((hi ^ rsw) * 8)]);
#pragma unroll
        for (int ni = 0; ni < NI; ++ni)
            bf[ni] = *reinterpret_cast<const s16x8*>(
                &sm[s][1][(wn * NI * 16 + ni * 16 + lo) * 32 + ((hi ^ rsw) * 8)]);
        __builtin_amdgcn_s_setprio(1);
#pragma unroll
        for (int mi = 0; mi < 8; ++mi)
#pragma unroll
            for (int ni = 0; ni < NI; ++ni)
                acc[mi][ni] = __builtin_amdgcn_mfma_f32_16x16x32_bf16(af[mi], bf[ni], acc[mi][ni], 0, 0, 0);
        __builtin_amdgcn_s_setprio(0);
    }
    const int rbase = row0 + wm * 128 + hi * 4;
    const int cbase = col0 + wn * NI * 16 + lo;
    if constexpr (BF16OUT) {
        __hip_bfloat16* C = (__hip_bfloat16*)Cv;
#pragma unroll
        for (int mi = 0; mi < 8; ++mi)
#pragma unroll
            for (int ni = 0; ni < NI; ++ni)
#pragma unroll
                for (int r = 0; r < 4; ++r)
                    C[(size_t)(rbase + mi * 16 + r) * N + cbase + ni * 16] =
                        __float2bfloat16(acc[mi][ni][r]);
    } else {
        float* C = (float*)Cv;
#pragma unroll
        for (int mi = 0; mi < 8; ++mi)
#pragma unroll
            for (int ni = 0; ni < NI; ++ni)
#pragma unroll
                for (int r = 0; r < 4; ++r)
                    C[(size_t)(rbase + mi * 16 + r) * N + cbase + ni * 16] = acc[mi][ni][r];
    }
}

// ---------------- flash attention: 4 waves x 32 q-rows, 32x32 MFMA, LDS-free P ----------------
// r14-exact (proven 87.7 us): 2 blocks/CU, 8 waves/CU is the measured optimum of
// the {LDS-port-traffic x latency-hiding} trade. XCD-chunked KV slices L2-resident.
__global__ __launch_bounds__(256, 2)
void attn_kernel(const __hip_bfloat16* __restrict__ Qr,
                 const __hip_bfloat16* __restrict__ Kr,
                 const __hip_bfloat16* __restrict__ Vt,
                 const float* __restrict__ maskb,
                 __hip_bfloat16* __restrict__ Oo) {
    const int S = 2048;
    const int id = blockIdx.x;                          // 0..511
    const int v = (id & 7) * 64 + (id >> 3);            // XCD-chunked, bijective
    const int qt = v & 15;                              // 0..15 (128 q-rows/block)
    const int bh = v >> 4;                              // 0..31
    const int b = bh >> 4, h = bh & 15, kvh = h >> 2;
    const int tid = threadIdx.x;
    const int l = tid & 63, wv_ = tid >> 6;             // 4 waves
    const int lq = l & 31, hi2 = l >> 5;
    __shared__ __align__(16) __hip_bfloat16 Ks[2][64 * 128];   // [kv][d], chunk-swizzled
    __shared__ __align__(16) __hip_bfloat16 Vs[2][128 * 64];   // [d][kv], chunk-swizzled

    const __hip_bfloat16* Qb = Qr + (size_t)(b * 16 + h) * S * 128;
    const __hip_bfloat16* Kb = Kr + (size_t)(b * 4 + kvh) * S * 128;
    const __hip_bfloat16* Vb = Vt + (size_t)(b * 4 + kvh) * 128 * S;
    const float* mrow = maskb + b * S;

    // Q fragments (B-operand): col q = lq, k = d = ks*16 + hi2*8 + j
    const int qrow = qt * 128 + wv_ * 32 + lq;
    s16x8 qf[8];
#pragma unroll
    for (int ks = 0; ks < 8; ++ks)
        qf[ks] = *reinterpret_cast<const s16x8*>(Qb + (size_t)qrow * 128 + ks * 16 + hi2 * 8);

    float m_run = 0.f, l_run = 0.f;                     // exp2-domain; row q = lq lane-local
    f32x16 o[4];                                        // O^T[dv = dt*32+...][q = lq]
#pragma unroll
    for (int dt = 0; dt < 4; ++dt)
#pragma unroll
        for (int r = 0; r < 16; ++r) o[dt][r] = 0.f;
    const float scale2 = 0.12751682f;                   // 1/sqrt(128) * log2(e)

    // staging: 256 threads; K 64x16 chunks, V 128x8 chunks, 4 each
    const int krow = tid >> 4, kc8 = tid & 15;          // rows i*16+krow
    const int koff = (kc8 ^ (krow & 7)) * 8;
    const int vrow = tid >> 3, vc8 = tid & 7;           // rows i*32+vrow
    const int voff = (vc8 ^ (vrow & 7)) * 8;

    s16x8 kreg[4], vreg[4];
    auto load_tile = [&](int kv0) {
#pragma unroll
        for (int i = 0; i < 4; ++i)
            kreg[i] = *reinterpret_cast<const s16x8*>(
                Kb + (size_t)(kv0 + i * 16 + krow) * 128 + kc8 * 8);
#pragma unroll
        for (int i = 0; i < 4; ++i)
            vreg[i] = *reinterpret_cast<const s16x8*>(
                Vb + (size_t)(i * 32 + vrow) * S + kv0 + vc8 * 8);
    };

    auto body = [&](int kt, __hip_bfloat16* Kc, __hip_bfloat16* Vc) {
        const int kv0 = kt * 64;
        // mask bias: kv = kv0 + 32*sub + 8*r4 + 4*hi2 + j
        f32x4 bi[2][4];
#pragma unroll
        for (int sub = 0; sub < 2; ++sub)
#pragma unroll
            for (int r4 = 0; r4 < 4; ++r4)
                bi[sub][r4] = *reinterpret_cast<const f32x4*>(
                    mrow + kv0 + sub * 32 + r4 * 8 + hi2 * 4);
#pragma unroll
        for (int i = 0; i < 4; ++i)
            *reinterpret_cast<s16x8*>(Kc + (i * 16 + krow) * 128 + koff) = kreg[i];
#pragma unroll
        for (int i = 0; i < 4; ++i)
            *reinterpret_cast<s16x8*>(Vc + (i * 32 + vrow) * 64 + voff) = vreg[i];
        if (kt < 31) load_tile(kv0 + 64);               // stays in flight across barrier
        asm volatile("s_waitcnt lgkmcnt(0)" ::: "memory");  // writes visible
        asm volatile("s_barrier" ::: "memory");             // NO vmcnt drain

        // P^T = K Q^T: sc[sub] covers kv-subtile sub*32, cols q
        f32x16 sc[2];
#pragma unroll
        for (int sub = 0; sub < 2; ++sub)
#pragma unroll
            for (int r = 0; r < 16; ++r) sc[sub][r] = 0.f;
        __builtin_amdgcn_s_setprio(1);
#pragma unroll
        for (int sub = 0; sub < 2; ++sub) {
            const int kr = sub * 32 + lq;
            const int ksw = kr & 7;
#pragma unroll
            for (int ks = 0; ks < 8; ++ks) {
                s16x8 kf = *reinterpret_cast<const s16x8*>(
                    Kc + kr * 128 + (((ks * 2 + hi2) ^ ksw) * 8));
                sc[sub] = __builtin_amdgcn_mfma_f32_32x32x16_bf16(kf, qf[ks], sc[sub], 0, 0, 0);
            }
        }
        __builtin_amdgcn_s_setprio(0);
        // scale + bias
#pragma unroll
        for (int sub = 0; sub < 2; ++sub)
#pragma unroll
            for (int r = 0; r < 16; ++r)
                sc[sub][r] = fmaf(sc[sub][r], scale2, bi[sub][r >> 2][r & 3]);
        // local row-max (for rare-rescale guard; off critical path)
        float mx = sc[0][0];
#pragma unroll
        for (int sub = 0; sub < 2; ++sub)
#pragma unroll
            for (int r = 0; r < 16; ++r) mx = fmaxf(mx, sc[sub][r]);
        // speculative exp2 with current m_run (likely stable at 0)
        float ss = 0.f;
#pragma unroll
        for (int sub = 0; sub < 2; ++sub)
#pragma unroll
            for (int r = 0; r < 16; ++r) {
                sc[sub][r] = fexp2(sc[sub][r] - m_run);
                ss += sc[sub][r];
            }
        mx = fmaxf(mx, __shfl_xor(mx, 32));
        if (__ballot(mx > m_run + 11.5417f) != 0ull) {  // rare: correct the speculation
            const float mnew = fmaxf(m_run, mx);
            const float alpha = fexp2(m_run - mnew);
            m_run = mnew;
            l_run *= alpha;
            ss *= alpha;
#pragma unroll
            for (int sub = 0; sub < 2; ++sub)
#pragma unroll
                for (int r = 0; r < 16; ++r) sc[sub][r] *= alpha;
#pragma unroll
            for (int dt = 0; dt < 4; ++dt)
#pragma unroll
                for (int r = 0; r < 16; ++r) o[dt][r] *= alpha;  // q lane-local
        }
        ss += __shfl_xor(ss, 32);
        l_run += ss;
        // P -> bf16 words: wvp[r4g][t] = pk(kv j=2t,2t+1) of 4-block r4g (kv=8*r4g+4*hi2)
        unsigned int wvp[8][2];
#pragma unroll
        for (int g = 0; g < 8; ++g) {
            const int sub = g >> 2, r4 = g & 3;
            asm("v_cvt_pk_bf16_f32 %0, %1, %2"
                : "=v"(wvp[g][0]) : "v"(sc[sub][r4 * 4 + 0]), "v"(sc[sub][r4 * 4 + 1]));
            asm("v_cvt_pk_bf16_f32 %0, %1, %2"
                : "=v"(wvp[g][1]) : "v"(sc[sub][r4 * 4 + 2]), "v"(sc[sub][r4 * 4 + 3]));
        }
        // O^T += V^T P^T  (A = V^T rows dv; B = P^T cols q, k = kv)
        __builtin_amdgcn_s_setprio(1);
#pragma unroll
        for (int ks = 0; ks < 4; ++ks) {
            u32x2 r0 = __builtin_amdgcn_permlane32_swap(wvp[2 * ks][0], wvp[2 * ks + 1][0], false, false);
            u32x2 r1 = __builtin_amdgcn_permlane32_swap(wvp[2 * ks][1], wvp[2 * ks + 1][1], false, false);
            union { unsigned int u[4]; s16x8 v; } pf;
            pf.u[0] = r0.x; pf.u[1] = r1.x; pf.u[2] = r0.y; pf.u[3] = r1.y;
#pragma unroll
            for (int dt = 0; dt < 4; ++dt) {
                const int dvr = dt * 32 + lq;
                s16x8 vf = *reinterpret_cast<const s16x8*>(
                    Vc + dvr * 64 + (((ks * 2 + hi2) ^ (dvr & 7)) * 8));
                o[dt] = __builtin_amdgcn_mfma_f32_32x32x16_bf16(vf, pf.v, o[dt], 0, 0, 0);
            }
        }
        __builtin_amdgcn_s_setprio(0);
    };

    load_tile(0);
    for (int kt2 = 0; kt2 < 16; ++kt2) {                // x2 unroll: static LDS bases
        body(2 * kt2,     &Ks[0][0], &Vs[0][0]);
        body(2 * kt2 + 1, &Ks[1][0], &Vs[1][0]);
    }
    // epilogue: Oo[s][h*128 + dv] = o / l; q = lq lane-local, dv = dt*32+8*r4+4*hi2+j
    const float inv = 1.f / l_run;
    const size_t obase = (size_t)(b * S + qt * 128 + wv_ * 32 + lq) * 2048 + h * 128;
#pragma unroll
    for (int dt = 0; dt < 4; ++dt)
#pragma unroll
        for (int r4 = 0; r4 < 4; ++r4) {
            union { s16x4 v4; __hip_bfloat16 hh[4]; } u;
#pragma unroll
            for (int j = 0; j < 4; ++j)
                u.hh[j] = __float2bfloat16(o[dt][r4 * 4 + j] * inv);
            *reinterpret_cast<s16x4*>(&Oo[obase + dt * 32 + r4 * 8 + hi2 * 4]) = u.v4;
        }
}

// ---------------- host launch ----------------
extern "C" void kernel_launch(void* const* d_in, const int* in_sizes, int n_in,
                              void* d_out, int out_size, void* d_ws, size_t ws_size,
                              hipStream_t stream) {
    const float* x  = (const float*)d_in[0];
    const int* mask = (const int*)d_in[1];
    const float* Wq = (const float*)d_in[2];
    const float* Wk = (const float*)d_in[3];
    const float* Wv = (const float*)d_in[4];
    const float* Wo = (const float*)d_in[5];
    float* out = (float*)d_out;

    char* ws = (char*)d_ws;
    size_t off = 0;
    auto alloc = [&](size_t bytes) -> void* {
        void* p = ws + off;
        off += (bytes + 255) & ~(size_t)255;
        return p;
    };
    __hip_bfloat16* xb     = (__hip_bfloat16*)alloc(4096ULL * 2048 * 2);   // 16 MB
    __hip_bfloat16* wqkv_t = (__hip_bfloat16*)alloc(3072ULL * 2048 * 2);   // 12 MB
    __hip_bfloat16* wo_t   = (__hip_bfloat16*)alloc(2048ULL * 2048 * 2);   // 8 MB
    __hip_bfloat16* Qr     = (__hip_bfloat16*)alloc(2ULL * 16 * 2048 * 128 * 2); // 16 MB
    __hip_bfloat16* Kr     = (__hip_bfloat16*)alloc(2ULL * 4 * 2048 * 128 * 2);  // 4 MB
    __hip_bfloat16* Vt     = (__hip_bfloat16*)alloc(2ULL * 4 * 2048 * 128 * 2);  // 4 MB
    float*          cosT2  = (float*)alloc(64ULL * 2048 * 4);
    float*          sinT2  = (float*)alloc(64ULL * 2048 * 4);
    float*          maskb  = (float*)alloc(2ULL * 2048 * 4);
    __hip_bfloat16* attno  = (__hip_bfloat16*)alloc(4096ULL * 2048 * 2);   // 16 MB

    tables_prep<<<dim3(80), dim3(256), 0, stream>>>(cosT2, sinT2, mask, maskb);
    cast_f32_bf16<<<dim3(8192), dim3(256), 0, stream>>>(x, xb, 2097152);
    transpose_cast_all<<<dim3(160, 64), dim3(32, 8), 0, stream>>>(Wq, Wk, Wv, Wo, wqkv_t, wo_t);

    // QKV GEMM + RoPE/scatter epilogue: 256x256 tiles, grid 192 (NX=12, NY=16)
    gemm_qkv_fused<<<dim3(192), dim3(512), 0, stream>>>(xb, wqkv_t, cosT2, sinT2,
                                                        Qr, Kr, Vt, 2048);
    attn_kernel<<<dim3(512), dim3(256), 0, stream>>>(Qr, Kr, Vt, maskb, attno);
    // Wo: 256x128 tiles, 1-D grid 256 (NX=16, NY=16), fp32 output
    gemm256_bt<2, false><<<dim3(256), dim3(512), 0, stream>>>(attno, wo_t, out, 4096, 2048, 2048, 16);
}

// Round 20
// 204.539 us; speedup vs baseline: 1.1299x; 1.0330x over previous
//
#include <hip/hip_runtime.h>
#include <hip/hip_bf16.h>

typedef __attribute__((ext_vector_type(4))) float f32x4;
typedef __attribute__((ext_vector_type(16))) float f32x16;
typedef __attribute__((ext_vector_type(8))) short s16x8;
typedef __attribute__((ext_vector_type(4))) short s16x4;
typedef __attribute__((ext_vector_type(2))) unsigned int u32x2;

__device__ __forceinline__ float fexp2(float x) {   // 2^x
    float y; asm("v_exp_f32 %0, %1" : "=v"(y) : "v"(x)); return y;
}

// ---------------- mega-prep: RoPE tables (transposed) + mask bias + x cast +
// weight transposes, one launch (all BW-bound, independent block ranges) -------
// Q/K weight rows PERMUTED within each 128-row head: row p holds source column
// d(p) = 16*(p>>5) + (p&15) + 64*((p>>4)&1) -> RoPE pairs land 16 GEMM-output
// columns apart (same lane, adjacent ni) in the fused epilogue.
__global__ __launch_bounds__(256)
void mega_prep(const float* __restrict__ x, __hip_bfloat16* __restrict__ xb,
               const float* __restrict__ Wq, const float* __restrict__ Wk,
               const float* __restrict__ Wv, const float* __restrict__ Wo,
               __hip_bfloat16* __restrict__ wqkv_t, __hip_bfloat16* __restrict__ wo_t,
               float* __restrict__ cosT2, float* __restrict__ sinT2,
               const int* __restrict__ mask, float* __restrict__ mb) {
    __shared__ __align__(16) float t[32][33];
    const int bid = blockIdx.x, tid = threadIdx.x;
    if (bid < 64) {                                     // RoPE tables, j = bid
        const int j = bid;
        const float inv = exp2f(-(float)j * (13.287712379549449f / 64.f)); // 10000^(-j/64)
#pragma unroll
        for (int k = 0; k < 8; ++k) {
            const int s = k * 256 + tid;
            const float f = (float)s * inv;
            cosT2[j * 2048 + s] = cosf(f);
            sinT2[j * 2048 + s] = sinf(f);
        }
    } else if (bid < 80) {                              // mask -> additive bias
        const int idx = (bid - 64) * 256 + tid;
        mb[idx] = (mask[idx] == 0) ? -1e30f : 0.f;
    } else if (bid < 80 + 8192) {                       // x: fp32 -> bf16
        const int i = (bid - 80) * 256 + tid;
        f32x4 v = *reinterpret_cast<const f32x4*>(x + (size_t)i * 4);
        union { s16x4 v4; __hip_bfloat16 h[4]; } u;
#pragma unroll
        for (int j = 0; j < 4; ++j) u.h[j] = __float2bfloat16(v[j]);
        *reinterpret_cast<s16x4*>(xb + (size_t)i * 4) = u.v4;
    } else {                                            // weight transposes
        const int tt = bid - 8272;
        const int xseg = tt % 160;
        const int r0 = (tt / 160) * 32;
        const int tx = tid & 31, ty = tid >> 5;
        const float* src; __hip_bfloat16* dst; int C, c0; bool perm;
        if (xseg < 64)      { src = Wq; dst = wqkv_t;                  C = 2048; c0 = xseg * 32;        perm = true; }
        else if (xseg < 80) { src = Wk; dst = wqkv_t + 2048ULL * 2048; C = 512;  c0 = (xseg - 64) * 32; perm = true; }
        else if (xseg < 96) { src = Wv; dst = wqkv_t + 2560ULL * 2048; C = 512;  c0 = (xseg - 80) * 32; perm = false; }
        else                { src = Wo; dst = wo_t;                    C = 2048; c0 = (xseg - 96) * 32; perm = false; }
#pragma unroll
        for (int i = 0; i < 32; i += 8)
            t[ty + i][tx] = src[(size_t)(r0 + ty + i) * C + c0 + tx];
        __syncthreads();
#pragma unroll
        for (int i = 0; i < 32; i += 8) {
            int row = c0 + ty + i;                      // source column index
            if (perm)
                row = (row & ~127) + (row & 15) + 32 * ((row >> 4) & 3) + 16 * ((row >> 6) & 1);
            dst[(size_t)row * 2048 + r0 + tx] = __float2bfloat16(t[tx][ty + i]);
        }
    }
}

// ---------------- fused QKV GEMM: 256x256 tiles + RoPE/scatter epilogue ----------
__global__ __launch_bounds__(512, 1)
void gemm_qkv_fused(const __hip_bfloat16* __restrict__ A,
                    const __hip_bfloat16* __restrict__ Bt,
                    const float* __restrict__ cosT2, const float* __restrict__ sinT2,
                    __hip_bfloat16* __restrict__ Qr, __hip_bfloat16* __restrict__ Kr,
                    __hip_bfloat16* __restrict__ Vt, int K) {
    __shared__ __align__(16) __hip_bfloat16 sm[4][2][8192];
    const int tid = threadIdx.x;
    const int l = tid & 63, w = tid >> 6;               // 8 waves
    const int lo = l & 15, hi = l >> 4;
    const int wm = w >> 2, wn = w & 3;
    const int id = blockIdx.x, slot = id >> 3;          // grid 192, NX=12
    const int by = (id & 7) * 2 + slot / 12;
    const int bx = slot % 12;
    const int row0 = by * 256;
    const int col0 = bx * 256;
    const int nk = K >> 5;

    f32x4 acc[8][4];
#pragma unroll
    for (int mi = 0; mi < 8; ++mi)
#pragma unroll
        for (int ni = 0; ni < 4; ++ni) acc[mi][ni] = f32x4{0.f, 0.f, 0.f, 0.f};

    auto ldlds = [&](const __hip_bfloat16* gsrc, __hip_bfloat16* ldst) {
        __builtin_amdgcn_global_load_lds(
            (const __attribute__((address_space(1))) void*)gsrc,
            (__attribute__((address_space(3))) void*)ldst, 16, 0, 0);
    };
    auto stage = [&](int kt) {
        const int s = kt & 3, k0 = kt << 5;
#pragma unroll
        for (int i = 0; i < 2; ++i) {                   // A: 256 rows x 4 chunks
            const int c = i * 512 + tid;
            const int r = c >> 2, sw = ((c & 3) ^ ((r >> 1) & 3)) * 8;
            ldlds(A + (size_t)(row0 + r) * K + k0 + sw, &sm[s][0][c * 8]);
        }
#pragma unroll
        for (int i = 0; i < 2; ++i) {                   // B: 256 rows x 4 chunks
            const int c = i * 512 + tid;
            const int r = c >> 2, sw = ((c & 3) ^ ((r >> 1) & 3)) * 8;
            ldlds(Bt + (size_t)(col0 + r) * K + k0 + sw, &sm[s][1][c * 8]);
        }
    };

    stage(0); stage(1); stage(2);                       // 3 tiles ahead
    for (int kt = 0; kt < nk; ++kt) {
        const int s = kt & 3;
        if (kt < nk - 2)       asm volatile("s_waitcnt vmcnt(8)" ::: "memory");
        else if (kt == nk - 2) asm volatile("s_waitcnt vmcnt(4)" ::: "memory");
        else                   asm volatile("s_waitcnt vmcnt(0)" ::: "memory");
        asm volatile("s_waitcnt lgkmcnt(0)" ::: "memory");  // slot reads of kt-1 done
        asm volatile("s_barrier" ::: "memory");             // no compiler drain added
        if (kt + 3 < nk) stage(kt + 3);                     // into slot (kt-1)&3: safe

        s16x8 af[8], bf[4];
        const int rsw = ((lo >> 1) & 3);                // f(row), row base %16 == 0
#pragma unroll
        for (int mi = 0; mi < 8; ++mi)
            af[mi] = *reinterpret_cast<const s16x8*>(
                &sm[s][0][(wm * 128 + mi * 16 + lo) * 32 + ((hi ^ rsw) * 8)]);
#pragma unroll
        for (int ni = 0; ni < 4; ++ni)
            bf[ni] = *reinterpret_cast<const s16x8*>(
                &sm[s][1][(wn * 64 + ni * 16 + lo) * 32 + ((hi ^ rsw) * 8)]);
        __builtin_amdgcn_s_setprio(1);
#pragma unroll
        for (int mi = 0; mi < 8; ++mi)
#pragma unroll
            for (int ni = 0; ni < 4; ++ni)
                acc[mi][ni] = __builtin_amdgcn_mfma_f32_16x16x32_bf16(af[mi], bf[ni], acc[mi][ni], 0, 0, 0);
        __builtin_amdgcn_s_setprio(0);
    }

    const int rbase = row0 + wm * 128 + hi * 4;
    if (bx < 10) {
        // ---- Q or K block: RoPE in permuted-column space ----
        const int cw = col0 + wn * 64;                  // wave's 64-col block base
        const bool isQ = (bx < 8);
        const int head = (isQ ? cw : cw - 2048) >> 7;
        __hip_bfloat16* dst = isQ ? (Qr + ((size_t)head * 2048) * 128)
                                  : (Kr + ((size_t)head * 2048) * 128);
        const size_t bstride = (isQ ? 16ull : 4ull) * 2048 * 128;
        const int jbase = 32 * (wn & 1) + lo;           // j = jbase + 16*np
#pragma unroll
        for (int mi = 0; mi < 8; ++mi) {
            const int tok = rbase + mi * 16;
            const int b = tok >> 11, s0 = tok & 2047;
            __hip_bfloat16* drow = dst + b * bstride + (size_t)s0 * 128;
#pragma unroll
            for (int np = 0; np < 2; ++np) {
                const int j = jbase + 16 * np;
                const f32x4 c4 = *reinterpret_cast<const f32x4*>(cosT2 + j * 2048 + s0);
                const f32x4 s4 = *reinterpret_cast<const f32x4*>(sinT2 + j * 2048 + s0);
                const int ni0 = 2 * np, ni1 = 2 * np + 1;
                const int dd0 = j;                      // h=0: d = j
#pragma unroll
                for (int r = 0; r < 4; ++r) {
                    const float v0 = acc[mi][ni0][r], v1 = acc[mi][ni1][r];
                    drow[(size_t)r * 128 + dd0]      = __float2bfloat16(v0 * c4[r] - v1 * s4[r]);
                    drow[(size_t)r * 128 + dd0 + 64] = __float2bfloat16(v1 * c4[r] + v0 * s4[r]);
                }
            }
        }
    } else {
        // ---- V block: transpose-scatter to Vt[b][hh][d][s], s packed via r ----
        const int cw = col0 + wn * 64 - 2560;           // 0..511
        const int hh = cw >> 7;
#pragma unroll
        for (int mi = 0; mi < 8; ++mi) {
            const int tok = rbase + mi * 16;
            const int b = tok >> 11, s0 = tok & 2047;
#pragma unroll
            for (int ni = 0; ni < 4; ++ni) {
                const int dd = (cw & 127) + ni * 16 + lo;
                union { s16x4 v4; __hip_bfloat16 h[4]; } u;
#pragma unroll
                for (int r = 0; r < 4; ++r) u.h[r] = __float2bfloat16(acc[mi][ni][r]);
                *reinterpret_cast<s16x4*>(
                    &Vt[((size_t)(b * 4 + hh) * 128 + dd) * 2048 + s0]) = u.v4;
            }
        }
    }
}

// ---------------- 256-row-tile GEMM (Wo), counted-vmcnt 4-slot pipeline ----------
template<int NI, bool BF16OUT>
__global__ __launch_bounds__(512, 1)
void gemm256_bt(const __hip_bfloat16* __restrict__ A,
                const __hip_bfloat16* __restrict__ Bt,
                void* __restrict__ Cv, int M, int N, int K, int NX) {
    __shared__ __align__(16) __hip_bfloat16 sm[4][2][8192];
    const int tid = threadIdx.x;
    const int l = tid & 63, w = tid >> 6;               // 8 waves
    const int lo = l & 15, hi = l >> 4;
    const int wm = w >> 2, wn = w & 3;
    const int id = blockIdx.x, slot = id >> 3;
    const int by = (id & 7) * 2 + slot / NX;
    const int bx = slot % NX;
    const int row0 = by * 256;
    const int col0 = bx * (NI * 64);
    const int nk = K >> 5;

    f32x4 acc[8][NI];
#pragma unroll
    for (int mi = 0; mi < 8; ++mi)
#pragma unroll
        for (int ni = 0; ni < NI; ++ni) acc[mi][ni] = f32x4{0.f, 0.f, 0.f, 0.f};

    auto ldlds = [&](const __hip_bfloat16* gsrc, __hip_bfloat16* ldst) {
        __builtin_amdgcn_global_load_lds(
            (const __attribute__((address_space(1))) void*)gsrc,
            (__attribute__((address_space(3))) void*)ldst, 16, 0, 0);
    };
    auto stage = [&](int kt) {
        const int s = kt & 3, k0 = kt << 5;
#pragma unroll
        for (int i = 0; i < 2; ++i) {                   // A: 256 rows x 4 chunks
            const int c = i * 512 + tid;
            const int r = c >> 2, sw = ((c & 3) ^ ((r >> 1) & 3)) * 8;
            ldlds(A + (size_t)(row0 + r) * K + k0 + sw, &sm[s][0][c * 8]);
        }
        {                                               // B chunk set 0: 0..511
            const int c = tid;
            const int r = c >> 2, sw = ((c & 3) ^ ((r >> 1) & 3)) * 8;
            ldlds(Bt + (size_t)(col0 + r) * K + k0 + sw, &sm[s][1][c * 8]);
        }
        if constexpr (NI == 4) {
            const int c = 512 + tid;
            const int r = c >> 2, sw = ((c & 3) ^ ((r >> 1) & 3)) * 8;
            ldlds(Bt + (size_t)(col0 + r) * K + k0 + sw, &sm[s][1][c * 8]);
        }
    };

    stage(0); stage(1); stage(2);                       // 3 tiles ahead
    for (int kt = 0; kt < nk; ++kt) {
        const int s = kt & 3;
        if (kt < nk - 2) {
            if constexpr (NI == 4) asm volatile("s_waitcnt vmcnt(8)" ::: "memory");
            else                   asm volatile("s_waitcnt vmcnt(6)" ::: "memory");
        } else if (kt == nk - 2) {
            if constexpr (NI == 4) asm volatile("s_waitcnt vmcnt(4)" ::: "memory");
            else                   asm volatile("s_waitcnt vmcnt(3)" ::: "memory");
        } else {
            asm volatile("s_waitcnt vmcnt(0)" ::: "memory");
        }
        asm volatile("s_waitcnt lgkmcnt(0)" ::: "memory");  // slot reads of kt-1 done
        asm volatile("s_barrier" ::: "memory");             // no compiler drain added
        if (kt + 3 < nk) stage(kt + 3);                     // into slot (kt-1)&3: safe

        s16x8 af[8], bf[NI];
        const int rsw = ((lo >> 1) & 3);                // f(row), row base %16 == 0
#pragma unroll
        for (int mi = 0; mi < 8; ++mi)
            af[mi] = *reinterpret_cast<const s16x8*>(
                &sm[s][0][(wm * 128 + mi * 16 + lo) * 32 + ((hi ^ rsw) * 8)]);
#pragma unroll
        for (int ni = 0; ni < NI; ++ni)
            bf[ni] = *reinterpret_cast<const s16x8*>(
                &sm[s][1][(wn * NI * 16 + ni * 16 + lo) * 32 + ((hi ^ rsw) * 8)]);
        __builtin_amdgcn_s_setprio(1);
#pragma unroll
        for (int mi = 0; mi < 8; ++mi)
#pragma unroll
            for (int ni = 0; ni < NI; ++ni)
                acc[mi][ni] = __builtin_amdgcn_mfma_f32_16x16x32_bf16(af[mi], bf[ni], acc[mi][ni], 0, 0, 0);
        __builtin_amdgcn_s_setprio(0);
    }
    const int rbase = row0 + wm * 128 + hi * 4;
    const int cbase = col0 + wn * NI * 16 + lo;
    if constexpr (BF16OUT) {
        __hip_bfloat16* C = (__hip_bfloat16*)Cv;
#pragma unroll
        for (int mi = 0; mi < 8; ++mi)
#pragma unroll
            for (int ni = 0; ni < NI; ++ni)
#pragma unroll
                for (int r = 0; r < 4; ++r)
                    C[(size_t)(rbase + mi * 16 + r) * N + cbase + ni * 16] =
                        __float2bfloat16(acc[mi][ni][r]);
    } else {
        float* C = (float*)Cv;
#pragma unroll
        for (int mi = 0; mi < 8; ++mi)
#pragma unroll
            for (int ni = 0; ni < NI; ++ni)
#pragma unroll
                for (int r = 0; r < 4; ++r)
                    C[(size_t)(rbase + mi * 16 + r) * N + cbase + ni * 16] = acc[mi][ni][r];
    }
}

// ---------------- flash attention: 4 waves x 32 q-rows, 32x32 MFMA, LDS-free P ----------------
// r14 structure + K-swizzle widened to row&15: kf reads span 32 rows at 256B
// stride (same bank base); ^(row&7) left rows {r,r+8,r+16,r+24} on one chunk ->
// 4-way conflict on every kf b128. ^(row&15) spreads 32 rows over 16 chunks ->
// 2-way (free). Same involution on write (staging rows i*16+krow: &15 == krow).
__global__ __launch_bounds__(256, 2)
void attn_kernel(const __hip_bfloat16* __restrict__ Qr,
                 const __hip_bfloat16* __restrict__ Kr,
                 const __hip_bfloat16* __restrict__ Vt,
                 const float* __restrict__ maskb,
                 __hip_bfloat16* __restrict__ Oo) {
    const int S = 2048;
    const int id = blockIdx.x;                          // 0..511
    const int v = (id & 7) * 64 + (id >> 3);            // XCD-chunked, bijective
    const int qt = v & 15;                              // 0..15 (128 q-rows/block)
    const int bh = v >> 4;                              // 0..31
    const int b = bh >> 4, h = bh & 15, kvh = h >> 2;
    const int tid = threadIdx.x;
    const int l = tid & 63, wv_ = tid >> 6;             // 4 waves
    const int lq = l & 31, hi2 = l >> 5;
    __shared__ __align__(16) __hip_bfloat16 Ks[2][64 * 128];   // [kv][d], chunk-swizzled (&15)
    __shared__ __align__(16) __hip_bfloat16 Vs[2][128 * 64];   // [d][kv], chunk-swizzled (&7)

    const __hip_bfloat16* Qb = Qr + (size_t)(b * 16 + h) * S * 128;
    const __hip_bfloat16* Kb = Kr + (size_t)(b * 4 + kvh) * S * 128;
    const __hip_bfloat16* Vb = Vt + (size_t)(b * 4 + kvh) * 128 * S;
    const float* mrow = maskb + b * S;

    // Q fragments (B-operand): col q = lq, k = d = ks*16 + hi2*8 + j
    const int qrow = qt * 128 + wv_ * 32 + lq;
    s16x8 qf[8];
#pragma unroll
    for (int ks = 0; ks < 8; ++ks)
        qf[ks] = *reinterpret_cast<const s16x8*>(Qb + (size_t)qrow * 128 + ks * 16 + hi2 * 8);

    float m_run = 0.f, l_run = 0.f;                     // exp2-domain; row q = lq lane-local
    f32x16 o[4];                                        // O^T[dv = dt*32+...][q = lq]
#pragma unroll
    for (int dt = 0; dt < 4; ++dt)
#pragma unroll
        for (int r = 0; r < 16; ++r) o[dt][r] = 0.f;
    const float scale2 = 0.12751682f;                   // 1/sqrt(128) * log2(e)

    // staging: 256 threads; K 64x16 chunks, V 128x8 chunks, 4 each
    const int krow = tid >> 4, kc8 = tid & 15;          // rows i*16+krow
    const int koff = (kc8 ^ (krow & 15)) * 8;           // row&15 == krow for all i
    const int vrow = tid >> 3, vc8 = tid & 7;           // rows i*32+vrow
    const int voff = (vc8 ^ (vrow & 7)) * 8;

    s16x8 kreg[4], vreg[4];
    auto load_tile = [&](int kv0) {
#pragma unroll
        for (int i = 0; i < 4; ++i)
            kreg[i] = *reinterpret_cast<const s16x8*>(
                Kb + (size_t)(kv0 + i * 16 + krow) * 128 + kc8 * 8);
#pragma unroll
        for (int i = 0; i < 4; ++i)
            vreg[i] = *reinterpret_cast<const s16x8*>(
                Vb + (size_t)(i * 32 + vrow) * S + kv0 + vc8 * 8);
    };

    auto body = [&](int kt, __hip_bfloat16* Kc, __hip_bfloat16* Vc) {
        const int kv0 = kt * 64;
        // mask bias: kv = kv0 + 32*sub + 8*r4 + 4*hi2 + j
        f32x4 bi[2][4];
#pragma unroll
        for (int sub = 0; sub < 2; ++sub)
#pragma unroll
            for (int r4 = 0; r4 < 4; ++r4)
                bi[sub][r4] = *reinterpret_cast<const f32x4*>(
                    mrow + kv0 + sub * 32 + r4 * 8 + hi2 * 4);
#pragma unroll
        for (int i = 0; i < 4; ++i)
            *reinterpret_cast<s16x8*>(Kc + (i * 16 + krow) * 128 + koff) = kreg[i];
#pragma unroll
        for (int i = 0; i < 4; ++i)
            *reinterpret_cast<s16x8*>(Vc + (i * 32 + vrow) * 64 + voff) = vreg[i];
        if (kt < 31) load_tile(kv0 + 64);               // stays in flight across barrier
        asm volatile("s_waitcnt lgkmcnt(0)" ::: "memory");  // writes visible
        asm volatile("s_barrier" ::: "memory");             // NO vmcnt drain

        // P^T = K Q^T: sc[sub] covers kv-subtile sub*32, cols q
        f32x16 sc[2];
#pragma unroll
        for (int sub = 0; sub < 2; ++sub)
#pragma unroll
            for (int r = 0; r < 16; ++r) sc[sub][r] = 0.f;
        __builtin_amdgcn_s_setprio(1);
#pragma unroll
        for (int sub = 0; sub < 2; ++sub) {
            const int kr = sub * 32 + lq;
            const int ksw = kr & 15;                    // widened: 2-way not 4-way
#pragma unroll
            for (int ks = 0; ks < 8; ++ks) {
                s16x8 kf = *reinterpret_cast<const s16x8*>(
                    Kc + kr * 128 + (((ks * 2 + hi2) ^ ksw) * 8));
                sc[sub] = __builtin_amdgcn_mfma_f32_32x32x16_bf16(kf, qf[ks], sc[sub], 0, 0, 0);
            }
        }
        __builtin_amdgcn_s_setprio(0);
        // scale + bias
#pragma unroll
        for (int sub = 0; sub < 2; ++sub)
#pragma unroll
            for (int r = 0; r < 16; ++r)
                sc[sub][r] = fmaf(sc[sub][r], scale2, bi[sub][r >> 2][r & 3]);
        // local row-max (for rare-rescale guard; off critical path)
        float mx = sc[0][0];
#pragma unroll
        for (int sub = 0; sub < 2; ++sub)
#pragma unroll
            for (int r = 0; r < 16; ++r) mx = fmaxf(mx, sc[sub][r]);
        // speculative exp2 with current m_run (likely stable at 0)
        float ss = 0.f;
#pragma unroll
        for (int sub = 0; sub < 2; ++sub)
#pragma unroll
            for (int r = 0; r < 16; ++r) {
                sc[sub][r] = fexp2(sc[sub][r] - m_run);
                ss += sc[sub][r];
            }
        mx = fmaxf(mx, __shfl_xor(mx, 32));
        if (__ballot(mx > m_run + 11.5417f) != 0ull) {  // rare: correct the speculation
            const float mnew = fmaxf(m_run, mx);
            const float alpha = fexp2(m_run - mnew);
            m_run = mnew;
            l_run *= alpha;
            ss *= alpha;
#pragma unroll
            for (int sub = 0; sub < 2; ++sub)
#pragma unroll
                for (int r = 0; r < 16; ++r) sc[sub][r] *= alpha;
#pragma unroll
            for (int dt = 0; dt < 4; ++dt)
#pragma unroll
                for (int r = 0; r < 16; ++r) o[dt][r] *= alpha;  // q lane-local
        }
        ss += __shfl_xor(ss, 32);
        l_run += ss;
        // P -> bf16 words: wvp[r4g][t] = pk(kv j=2t,2t+1) of 4-block r4g (kv=8*r4g+4*hi2)
        unsigned int wvp[8][2];
#pragma unroll
        for (int g = 0; g < 8; ++g) {
            const int sub = g >> 2, r4 = g & 3;
            asm("v_cvt_pk_bf16_f32 %0, %1, %2"
                : "=v"(wvp[g][0]) : "v"(sc[sub][r4 * 4 + 0]), "v"(sc[sub][r4 * 4 + 1]));
            asm("v_cvt_pk_bf16_f32 %0, %1, %2"
                : "=v"(wvp[g][1]) : "v"(sc[sub][r4 * 4 + 2]), "v"(sc[sub][r4 * 4 + 3]));
        }
        // O^T += V^T P^T  (A = V^T rows dv; B = P^T cols q, k = kv)
        __builtin_amdgcn_s_setprio(1);
#pragma unroll
        for (int ks = 0; ks < 4; ++ks) {
            u32x2 r0 = __builtin_amdgcn_permlane32_swap(wvp[2 * ks][0], wvp[2 * ks + 1][0], false, false);
            u32x2 r1 = __builtin_amdgcn_permlane32_swap(wvp[2 * ks][1], wvp[2 * ks + 1][1], false, false);
            union { unsigned int u[4]; s16x8 v; } pf;
            pf.u[0] = r0.x; pf.u[1] = r1.x; pf.u[2] = r0.y; pf.u[3] = r1.y;
#pragma unroll
            for (int dt = 0; dt < 4; ++dt) {
                const int dvr = dt * 32 + lq;
                s16x8 vf = *reinterpret_cast<const s16x8*>(
                    Vc + dvr * 64 + (((ks * 2 + hi2) ^ (dvr & 7)) * 8));
                o[dt] = __builtin_amdgcn_mfma_f32_32x32x16_bf16(vf, pf.v, o[dt], 0, 0, 0);
            }
        }
        __builtin_amdgcn_s_setprio(0);
    };

    load_tile(0);
    for (int kt2 = 0; kt2 < 16; ++kt2) {                // x2 unroll: static LDS bases
        body(2 * kt2,     &Ks[0][0], &Vs[0][0]);
        body(2 * kt2 + 1, &Ks[1][0], &Vs[1][0]);
    }
    // epilogue: Oo[s][h*128 + dv] = o / l; q = lq lane-local, dv = dt*32+8*r4+4*hi2+j
    const float inv = 1.f / l_run;
    const size_t obase = (size_t)(b * S + qt * 128 + wv_ * 32 + lq) * 2048 + h * 128;
#pragma unroll
    for (int dt = 0; dt < 4; ++dt)
#pragma unroll
        for (int r4 = 0; r4 < 4; ++r4) {
            union { s16x4 v4; __hip_bfloat16 hh[4]; } u;
#pragma unroll
            for (int j = 0; j < 4; ++j)
                u.hh[j] = __float2bfloat16(o[dt][r4 * 4 + j] * inv);
            *reinterpret_cast<s16x4*>(&Oo[obase + dt * 32 + r4 * 8 + hi2 * 4]) = u.v4;
        }
}

// ---------------- host launch ----------------
extern "C" void kernel_launch(void* const* d_in, const int* in_sizes, int n_in,
                              void* d_out, int out_size, void* d_ws, size_t ws_size,
                              hipStream_t stream) {
    const float* x  = (const float*)d_in[0];
    const int* mask = (const int*)d_in[1];
    const float* Wq = (const float*)d_in[2];
    const float* Wk = (const float*)d_in[3];
    const float* Wv = (const float*)d_in[4];
    const float* Wo = (const float*)d_in[5];
    float* out = (float*)d_out;

    char* ws = (char*)d_ws;
    size_t off = 0;
    auto alloc = [&](size_t bytes) -> void* {
        void* p = ws + off;
        off += (bytes + 255) & ~(size_t)255;
        return p;
    };
    __hip_bfloat16* xb     = (__hip_bfloat16*)alloc(4096ULL * 2048 * 2);   // 16 MB
    __hip_bfloat16* wqkv_t = (__hip_bfloat16*)alloc(3072ULL * 2048 * 2);   // 12 MB
    __hip_bfloat16* wo_t   = (__hip_bfloat16*)alloc(2048ULL * 2048 * 2);   // 8 MB
    __hip_bfloat16* Qr     = (__hip_bfloat16*)alloc(2ULL * 16 * 2048 * 128 * 2); // 16 MB
    __hip_bfloat16* Kr     = (__hip_bfloat16*)alloc(2ULL * 4 * 2048 * 128 * 2);  // 4 MB
    __hip_bfloat16* Vt     = (__hip_bfloat16*)alloc(2ULL * 4 * 2048 * 128 * 2);  // 4 MB
    float*          cosT2  = (float*)alloc(64ULL * 2048 * 4);
    float*          sinT2  = (float*)alloc(64ULL * 2048 * 4);
    float*          maskb  = (float*)alloc(2ULL * 2048 * 4);
    __hip_bfloat16* attno  = (__hip_bfloat16*)alloc(4096ULL * 2048 * 2);   // 16 MB

    // prep: tables(64) + mask(16) + cast(8192) + transposes(160*64=10240)
    mega_prep<<<dim3(18512), dim3(256), 0, stream>>>(x, xb, Wq, Wk, Wv, Wo,
                                                     wqkv_t, wo_t, cosT2, sinT2,
                                                     mask, maskb);
    // QKV GEMM + RoPE/scatter epilogue: 256x256 tiles, grid 192 (NX=12, NY=16)
    gemm_qkv_fused<<<dim3(192), dim3(512), 0, stream>>>(xb, wqkv_t, cosT2, sinT2,
                                                        Qr, Kr, Vt, 2048);
    attn_kernel<<<dim3(512), dim3(256), 0, stream>>>(Qr, Kr, Vt, maskb, attno);
    // Wo: 256x128 tiles, 1-D grid 256 (NX=16, NY=16), fp32 output
    gemm256_bt<2, false><<<dim3(256), dim3(512), 0, stream>>>(attno, wo_t, out, 4096, 2048, 2048, 16);
}